// Round 1
// baseline (744.438 us; speedup 1.0000x reference)
//
#include <hip/hip_runtime.h>

#define S_ 1024
#define E_ 768
#define H_ 12
#define R_ 32
#define D_ 64
#define RS_ 1056  // R_+S_

// ---------------------------------------------------------------------------
// Kernel 1: per-head Q/K projections.  q[b,h,s,o] = sum_d x[b,s,h,d]*W[o,d]
// Output layout [B,H,S,64] f32.
// ---------------------------------------------------------------------------
__global__ __launch_bounds__(256) void qk_proj(const float* __restrict__ query,
                                               const float* __restrict__ key,
                                               const float* __restrict__ Wq,
                                               const float* __restrict__ Wk,
                                               float* __restrict__ Qo,
                                               float* __restrict__ Ko) {
  // grid = B * H * (S/16) = 2*12*64 = 1536
  int blk = blockIdx.x;
  int st = blk & 63;            // 64 s-tiles of 16 rows
  int h  = (blk >> 6) % H_;
  int b  = blk / (64 * H_);
  int tid = threadIdx.x;

  __shared__ float Wqt[64][65];   // transposed, padded
  __shared__ float Wkt[64][65];
  __shared__ float xq[16][64];
  __shared__ float xk[16][64];

  for (int i = tid; i < 4096; i += 256) {
    int o = i >> 6, d = i & 63;
    Wqt[d][o] = Wq[i];
    Wkt[d][o] = Wk[i];
  }
  int s0 = st * 16;
  for (int i = tid; i < 1024; i += 256) {
    int r = i >> 6, d = i & 63;
    long addr = ((long)(b * S_ + s0 + r) * E_) + h * 64 + d;
    xq[r][d] = query[addr];
    xk[r][d] = key[addr];
  }
  __syncthreads();

  int o = tid & 63;
  int rg = tid >> 6;  // 0..3, each handles 4 rows
  for (int rr = 0; rr < 4; ++rr) {
    int r = rg * 4 + rr;
    float aq = 0.f, ak = 0.f;
#pragma unroll
    for (int d = 0; d < 64; ++d) {
      aq += xq[r][d] * Wqt[d][o];
      ak += xk[r][d] * Wkt[d][o];
    }
    long outp = ((long)((b * H_ + h) * S_) + s0 + r) * 64 + o;
    Qo[outp] = aq;
    Ko[outp] = ak;
  }
}

// ---------------------------------------------------------------------------
// Kernel 2: value projection.  VP[b,h,r,d] = sum_s value[b,s,h,d]*Wv[r,s]+bv[r]
// Output layout [B,H,RS,64] f32 (rules occupy r=0..31, keys r=32..1055).
// ---------------------------------------------------------------------------
__global__ __launch_bounds__(256) void v_proj(const float* __restrict__ value,
                                              const float* __restrict__ Wv,
                                              const float* __restrict__ bv,
                                              float* __restrict__ VP) {
  // grid = (B*H) * (RS/16) = 24 * 66 = 1584
  int blk = blockIdx.x;
  int rt = blk % 66;
  int bh = blk / 66;
  int b = bh / H_, h = bh % H_;
  int tid = threadIdx.x;
  int d = tid & 63, t4 = tid >> 6;

  __shared__ float Vl[64][64];
  __shared__ float Wl[16][64];

  float acc[4] = {0.f, 0.f, 0.f, 0.f};
  int r0 = rt * 16;
  for (int sblk = 0; sblk < S_; sblk += 64) {
    __syncthreads();
    for (int i = tid; i < 4096; i += 256) {
      int s = i >> 6, dd = i & 63;
      Vl[s][dd] = value[((long)(b * S_ + sblk + s) * E_) + h * 64 + dd];
    }
    for (int i = tid; i < 1024; i += 256) {
      int rr = i >> 6, ss = i & 63;
      Wl[rr][ss] = Wv[(long)(r0 + rr) * S_ + sblk + ss];
    }
    __syncthreads();
#pragma unroll 8
    for (int s = 0; s < 64; ++s) {
      float vv = Vl[s][d];
      acc[0] += vv * Wl[t4][s];
      acc[1] += vv * Wl[t4 + 4][s];
      acc[2] += vv * Wl[t4 + 8][s];
      acc[3] += vv * Wl[t4 + 12][s];
    }
  }
#pragma unroll
  for (int jj = 0; jj < 4; ++jj) {
    int r = r0 + t4 + 4 * jj;
    VP[((long)bh * RS_ + r) * 64 + d] = acc[jj] + bv[r];
  }
}

// ---------------------------------------------------------------------------
// Kernel 3: fused attention: energy=8*QK^T, softmax over keys; fuzzy z +
// softmax over rules; out = all_w @ VP^T.  Writes AO in [B,S,E] layout.
// ---------------------------------------------------------------------------
__global__ __launch_bounds__(256) void attn(const float* __restrict__ Q,
                                            const float* __restrict__ K,
                                            const float* __restrict__ VP,
                                            const float* __restrict__ RK,
                                            const float* __restrict__ RW,
                                            float* __restrict__ AO) {
  // grid = (B*H) * (S/8) = 24 * 128 = 3072
  int blk = blockIdx.x;
  int qt = blk & 127;
  int bh = blk >> 7;
  int b = bh / H_, h = bh % H_;
  int tid = threadIdx.x;

  __shared__ float qlds[8][64];
  __shared__ float e[8][1024];
  __shared__ float fw[8][32];
  __shared__ float red[4][8][64];

  int s0 = qt * 8;
  const float* Qbase = Q + ((long)bh * S_ + s0) * 64;
  for (int i = tid; i < 512; i += 256) qlds[i >> 6][i & 63] = Qbase[i];
  __syncthreads();

  // fuzzy branch: 8 rows x 32 rules = 256 threads
  {
    int row = tid >> 5, r = tid & 31;
    const float* rk = RK + ((long)h * R_ + r) * 64;
    const float* rw = RW + ((long)h * R_ + r) * 64;
    float z = 0.f;
#pragma unroll
    for (int d = 0; d < 64; ++d) {
      float df = (qlds[row][d] * 0.125f - rk[d]) / rw[d];
      z += df * df;
    }
    z *= -1.f / 128.f;  // mean(-0.5 * .^2)
    float m = z;
    for (int off = 16; off; off >>= 1) m = fmaxf(m, __shfl_xor(m, off, 32));
    float p = __expf(z - m);
    float l = p;
    for (int off = 16; off; off >>= 1) l += __shfl_xor(l, off, 32);
    fw[row][r] = p / l;
  }

  // energy: each thread owns one key per iteration, dots vs 8 q rows
  const float* Kbase = K + (long)bh * S_ * 64;
  for (int k0 = 0; k0 < S_; k0 += 256) {
    int k = k0 + tid;
    const float4* kr = (const float4*)(Kbase + (long)k * 64);
    float acc[8] = {0, 0, 0, 0, 0, 0, 0, 0};
#pragma unroll
    for (int d4 = 0; d4 < 16; ++d4) {
      float4 kv = kr[d4];
#pragma unroll
      for (int row = 0; row < 8; ++row) {
        const float* qp = &qlds[row][d4 * 4];
        acc[row] += kv.x * qp[0] + kv.y * qp[1] + kv.z * qp[2] + kv.w * qp[3];
      }
    }
#pragma unroll
    for (int row = 0; row < 8; ++row) e[row][k] = acc[row] * 8.f;
  }
  __syncthreads();

  // softmax per row over 1024 keys: 8 rows x 32 lanes
  {
    int row = tid >> 5, l32 = tid & 31;
    float m = -1e30f;
    for (int i = l32; i < S_; i += 32) m = fmaxf(m, e[row][i]);
    for (int off = 16; off; off >>= 1) m = fmaxf(m, __shfl_xor(m, off, 32));
    float sum = 0.f;
    for (int i = l32; i < S_; i += 32) {
      float p = __expf(e[row][i] - m);
      e[row][i] = p;
      sum += p;
    }
    for (int off = 16; off; off >>= 1) sum += __shfl_xor(sum, off, 32);
    float inv = 1.f / sum;
    for (int i = l32; i < S_; i += 32) e[row][i] *= inv;
  }
  __syncthreads();

  // PV: thread (d, g); group g covers rules [8g,8g+8) and keys [256g,256g+256)
  int d = tid & 63, g = tid >> 6;
  const float* vb = VP + (long)bh * RS_ * 64;
  float acc[8] = {0, 0, 0, 0, 0, 0, 0, 0};
  for (int r = g * 8; r < g * 8 + 8; ++r) {
    float vv = vb[(long)r * 64 + d];
#pragma unroll
    for (int row = 0; row < 8; ++row) acc[row] += fw[row][r] * vv;
  }
  for (int k = g * 256; k < g * 256 + 256; ++k) {
    float vv = vb[(long)(R_ + k) * 64 + d];
#pragma unroll
    for (int row = 0; row < 8; ++row) acc[row] += e[row][k] * vv;
  }
#pragma unroll
  for (int row = 0; row < 8; ++row) red[g][row][d] = acc[row];
  __syncthreads();

  for (int i = tid; i < 512; i += 256) {
    int row = i >> 6, dd = i & 63;
    float v = red[0][row][dd] + red[1][row][dd] + red[2][row][dd] + red[3][row][dd];
    AO[((long)(b * S_ + s0 + row) * E_) + h * 64 + dd] = v;
  }
}

// ---------------------------------------------------------------------------
// Kernel 4: output projection  out[n,e] = sum_f X[n,f]*Wo[e,f] + bo[e]
// ---------------------------------------------------------------------------
__global__ __launch_bounds__(256) void out_proj(const float* __restrict__ X,
                                                const float* __restrict__ Wo,
                                                const float* __restrict__ bo,
                                                float* __restrict__ Out) {
  // grid = (2048/16) * (768/64) = 128 * 12 = 1536
  int blk = blockIdx.x;
  int ct = blk % 12;
  int rt = blk / 12;
  int tid = threadIdx.x;
  int ecol = tid & 63, rg = tid >> 6;

  __shared__ float Xl[16][64];
  __shared__ float Wt[64][65];

  float acc[4] = {0.f, 0.f, 0.f, 0.f};
  int e0 = ct * 64, r0 = rt * 16;
  for (int f0 = 0; f0 < E_; f0 += 64) {
    __syncthreads();
    for (int i = tid; i < 1024; i += 256) {
      int rr = i >> 6, ff = i & 63;
      Xl[rr][ff] = X[(long)(r0 + rr) * E_ + f0 + ff];
    }
    for (int i = tid; i < 4096; i += 256) {
      int ii = i >> 6, jj = i & 63;  // ii: e index, jj: f index
      Wt[jj][ii] = Wo[(long)(e0 + ii) * E_ + f0 + jj];
    }
    __syncthreads();
#pragma unroll 8
    for (int f = 0; f < 64; ++f) {
      float w = Wt[f][ecol];
      acc[0] += Xl[rg * 4 + 0][f] * w;
      acc[1] += Xl[rg * 4 + 1][f] * w;
      acc[2] += Xl[rg * 4 + 2][f] * w;
      acc[3] += Xl[rg * 4 + 3][f] * w;
    }
  }
  float bias = bo[e0 + ecol];
#pragma unroll
  for (int rr = 0; rr < 4; ++rr) {
    Out[(long)(r0 + rg * 4 + rr) * E_ + e0 + ecol] = acc[rr] + bias;
  }
}

extern "C" void kernel_launch(void* const* d_in, const int* in_sizes, int n_in,
                              void* d_out, int out_size, void* d_ws, size_t ws_size,
                              hipStream_t stream) {
  const float* query = (const float*)d_in[0];
  const float* key   = (const float*)d_in[1];
  const float* value = (const float*)d_in[2];
  const float* rk    = (const float*)d_in[3];
  const float* rw    = (const float*)d_in[4];
  const float* Wq    = (const float*)d_in[5];
  const float* Wk    = (const float*)d_in[6];
  const float* Wv    = (const float*)d_in[7];
  const float* bv    = (const float*)d_in[8];
  const float* Wo    = (const float*)d_in[9];
  const float* bo    = (const float*)d_in[10];
  float* out = (float*)d_out;

  float* Qb = (float*)d_ws;                       // 2*12*1024*64 f32
  float* Kb = Qb + (long)2 * 12 * 1024 * 64;      // 2*12*1024*64 f32
  float* VP = Kb + (long)2 * 12 * 1024 * 64;      // 2*12*1056*64 f32
  float* AO = VP + (long)2 * 12 * 1056 * 64;      // 2*1024*768  f32

  qk_proj<<<1536, 256, 0, stream>>>(query, key, Wq, Wk, Qb, Kb);
  v_proj<<<24 * 66, 256, 0, stream>>>(value, Wv, bv, VP);
  attn<<<24 * 128, 256, 0, stream>>>(Qb, Kb, VP, rk, rw, AO);
  out_proj<<<128 * 12, 256, 0, stream>>>(AO, Wo, bo, out);
}

// Round 5
// 279.714 us; speedup vs baseline: 2.6614x; 2.6614x over previous
//
#include <hip/hip_runtime.h>

#define S_ 1024
#define E_ 768
#define H_ 12
#define R_ 32
#define D_ 64
#define RS_ 1056  // R_+S_

typedef _Float16 f16x8 __attribute__((ext_vector_type(8)));
typedef __bf16   bf16x8 __attribute__((ext_vector_type(8)));
typedef float    f32x4 __attribute__((ext_vector_type(4)));

__device__ __forceinline__ f32x4 mf16(f16x8 a, f16x8 b, f32x4 c) {
  return __builtin_amdgcn_mfma_f32_16x16x32_f16(a, b, c, 0, 0, 0);
}
__device__ __forceinline__ f32x4 mbf(bf16x8 a, bf16x8 b, f32x4 c) {
  return __builtin_amdgcn_mfma_f32_16x16x32_bf16(a, b, c, 0, 0, 0);
}

// ---------------------------------------------------------------------------
// Prep: fold fuzzy-rule quadratic form into two GEMM operand matrices.
// z[q][r] = sum_d Qh^2 * W1' + sum_d Qh * W2' + c'[r], with Qh = 8*q.
// W1' = -winv^2/524288, W2' = rk*winv^2/4096, c' = -sum(rk^2*winv^2)/128.
// ---------------------------------------------------------------------------
__global__ __launch_bounds__(64) void prep_rules(const float* __restrict__ RK,
                                                 const float* __restrict__ RW,
                                                 __bf16* __restrict__ W1b,
                                                 __bf16* __restrict__ W2b,
                                                 float* __restrict__ cb) {
  int hr = blockIdx.x;  // 0..383 = h*32 + r
  int d = threadIdx.x;
  long idx = (long)hr * 64 + d;
  float w = RW[idx];
  float wi = 1.0f / w;
  float w2 = wi * wi;
  float rk = RK[idx];
  W1b[idx] = (__bf16)(-w2 * (1.0f / 524288.0f));
  W2b[idx] = (__bf16)(rk * w2 * (1.0f / 4096.0f));
  float part = rk * rk * w2;
  part += __shfl_xor(part, 1);
  part += __shfl_xor(part, 2);
  part += __shfl_xor(part, 4);
  part += __shfl_xor(part, 8);
  part += __shfl_xor(part, 16);
  part += __shfl_xor(part, 32);
  if (d == 0) cb[hr] = -part * (1.0f / 128.0f);
}

// ---------------------------------------------------------------------------
// Kernel 1: per-head Q/K projections -> f16, Q pre-scaled by 8.
// ---------------------------------------------------------------------------
__global__ __launch_bounds__(256) void qk_proj(const float* __restrict__ query,
                                               const float* __restrict__ key,
                                               const float* __restrict__ Wq,
                                               const float* __restrict__ Wk,
                                               _Float16* __restrict__ Qh,
                                               _Float16* __restrict__ Kh) {
  int blk = blockIdx.x;
  int st = blk & 63;
  int h  = (blk >> 6) % H_;
  int b  = blk / (64 * H_);
  int tid = threadIdx.x;

  __shared__ float Wqt[64][65];
  __shared__ float Wkt[64][65];
  __shared__ float xq[16][64];
  __shared__ float xk[16][64];

  for (int i = tid; i < 4096; i += 256) {
    int o = i >> 6, d = i & 63;
    Wqt[d][o] = Wq[i];
    Wkt[d][o] = Wk[i];
  }
  int s0 = st * 16;
  for (int i = tid; i < 1024; i += 256) {
    int r = i >> 6, d = i & 63;
    long addr = ((long)(b * S_ + s0 + r) * E_) + h * 64 + d;
    xq[r][d] = query[addr];
    xk[r][d] = key[addr];
  }
  __syncthreads();

  int o = tid & 63;
  int rg = tid >> 6;
  for (int rr = 0; rr < 4; ++rr) {
    int r = rg * 4 + rr;
    float aq = 0.f, ak = 0.f;
#pragma unroll
    for (int d = 0; d < 64; ++d) {
      aq += xq[r][d] * Wqt[d][o];
      ak += xk[r][d] * Wkt[d][o];
    }
    long outp = ((long)((b * H_ + h) * S_) + s0 + r) * 64 + o;
    Qh[outp] = (_Float16)(aq * 8.0f);
    Kh[outp] = (_Float16)ak;
  }
}

// ---------------------------------------------------------------------------
// Kernel 2: value projection -> TRANSPOSED f16 [B,H,64,RS] (rules first).
// ---------------------------------------------------------------------------
__global__ __launch_bounds__(256) void v_proj(const float* __restrict__ value,
                                              const float* __restrict__ Wv,
                                              const float* __restrict__ bv,
                                              _Float16* __restrict__ VPT) {
  int blk = blockIdx.x;
  int rt = blk % 66;
  int bh = blk / 66;
  int b = bh / H_, h = bh % H_;
  int tid = threadIdx.x;
  int d = tid & 63, t4 = tid >> 6;

  __shared__ float Vl[64][64];
  __shared__ float Wl[16][64];

  float acc[4] = {0.f, 0.f, 0.f, 0.f};
  int r0 = rt * 16;
  for (int sblk = 0; sblk < S_; sblk += 64) {
    __syncthreads();
    for (int i = tid; i < 4096; i += 256) {
      int s = i >> 6, dd = i & 63;
      Vl[s][dd] = value[((long)(b * S_ + sblk + s) * E_) + h * 64 + dd];
    }
    for (int i = tid; i < 1024; i += 256) {
      int rr = i >> 6, ss = i & 63;
      Wl[rr][ss] = Wv[(long)(r0 + rr) * S_ + sblk + ss];
    }
    __syncthreads();
#pragma unroll 8
    for (int s = 0; s < 64; ++s) {
      float vv = Vl[s][d];
      acc[0] += vv * Wl[t4][s];
      acc[1] += vv * Wl[t4 + 4][s];
      acc[2] += vv * Wl[t4 + 8][s];
      acc[3] += vv * Wl[t4 + 12][s];
    }
  }
  __syncthreads();
  float* resf = (float*)Vl;  // reuse: [16][68]
#pragma unroll
  for (int jj = 0; jj < 4; ++jj) {
    int rl = t4 + 4 * jj;
    resf[rl * 68 + d] = acc[jj] + bv[r0 + rl];
  }
  __syncthreads();
  int rr = tid & 15, d0 = tid >> 4;
#pragma unroll
  for (int j2 = 0; j2 < 4; ++j2) {
    int dd = d0 + 16 * j2;
    VPT[((long)bh * 64 + dd) * RS_ + r0 + rr] = (_Float16)resf[rr * 68 + dd];
  }
}

// ---------------------------------------------------------------------------
// Kernel 3: MFMA flash attention + fuzzy-rule branch.
// Wave pairs: each pair owns 16 q-rows; wave 0 = keys 0..511 + fuzzy + merge,
// wave 1 = keys 512..1023. O accumulated transposed [64d x 16q] per wave.
// ---------------------------------------------------------------------------
__global__ __launch_bounds__(256) void attn_mfma(
    const _Float16* __restrict__ Qh, const _Float16* __restrict__ Kh,
    const _Float16* __restrict__ VPT, const __bf16* __restrict__ W1b,
    const __bf16* __restrict__ W2b, const float* __restrict__ cb,
    float* __restrict__ AO) {
  __shared__ alignas(16) _Float16 Plds[4][16][40];
  __shared__ alignas(16) _Float16 fwlds[2][16][40];
  __shared__ float OBl[2][64][17];
  __shared__ float mrgM[2][16];
  __shared__ float mrgL[2][16];
  __shared__ float Olds[2][16][68];

  int tid = threadIdx.x;
  int p = tid >> 7;
  int wv = (tid >> 6) & 1;
  int l = tid & 63;
  int lo = l & 15, g = l >> 4;
  int ws4 = tid >> 6;

  int pidx = blockIdx.x * 2 + p;
  int bh = pidx >> 6;
  int qt = pidx & 63;
  int b = bh / H_, h = bh % H_;
  int s0 = qt * 16;

  const _Float16* Qw = Qh + ((long)bh * S_ + s0) * 64;
  const _Float16* Kw = Kh + (long)bh * S_ * 64;
  const _Float16* Vw = VPT + (long)bh * 64 * RS_;

  f16x8 qa0 = *(const f16x8*)(Qw + (long)lo * 64 + g * 8);
  f16x8 qa1 = *(const f16x8*)(Qw + (long)lo * 64 + 32 + g * 8);

  // ---- fuzzy branch (wave 0 of pair only): z via 8 bf16 mfmas + softmax(R)
  if (wv == 0) {
    bf16x8 qsq0, qsq1, qbf0, qbf1;
#pragma unroll
    for (int j = 0; j < 8; ++j) {
      float a0 = (float)qa0[j], a1 = (float)qa1[j];
      qbf0[j] = (__bf16)a0;
      qbf1[j] = (__bf16)a1;
      qsq0[j] = (__bf16)(a0 * a0);
      qsq1[j] = (__bf16)(a1 * a1);
    }
    f32x4 z[2];
#pragma unroll
    for (int t = 0; t < 2; ++t) {
      float cc = cb[h * R_ + t * 16 + lo];
#pragma unroll
      for (int j = 0; j < 4; ++j) z[t][j] = cc;
      const __bf16* w1p = W1b + ((long)h * R_ + t * 16 + lo) * 64;
      const __bf16* w2p = W2b + ((long)h * R_ + t * 16 + lo) * 64;
      bf16x8 b10 = *(const bf16x8*)(w1p + g * 8);
      bf16x8 b11 = *(const bf16x8*)(w1p + 32 + g * 8);
      bf16x8 b20 = *(const bf16x8*)(w2p + g * 8);
      bf16x8 b21 = *(const bf16x8*)(w2p + 32 + g * 8);
      z[t] = mbf(qsq0, b10, z[t]);
      z[t] = mbf(qsq1, b11, z[t]);
      z[t] = mbf(qbf0, b20, z[t]);
      z[t] = mbf(qbf1, b21, z[t]);
    }
#pragma unroll
    for (int r = 0; r < 4; ++r) {
      float cm = fmaxf(z[0][r], z[1][r]);
      cm = fmaxf(cm, __shfl_xor(cm, 1));
      cm = fmaxf(cm, __shfl_xor(cm, 2));
      cm = fmaxf(cm, __shfl_xor(cm, 4));
      cm = fmaxf(cm, __shfl_xor(cm, 8));
      float e0 = __expf(z[0][r] - cm);
      float e1 = __expf(z[1][r] - cm);
      float sum = e0 + e1;
      sum += __shfl_xor(sum, 1);
      sum += __shfl_xor(sum, 2);
      sum += __shfl_xor(sum, 4);
      sum += __shfl_xor(sum, 8);
      float inv = 1.0f / sum;
      fwlds[p][g * 4 + r][lo] = (_Float16)(e0 * inv);
      fwlds[p][g * 4 + r][16 + lo] = (_Float16)(e1 * inv);
    }
  }

  // ---- flash key loop (each wave: 16 chunks of 32 keys)
  f32x4 O[4];
  float m[4], ell[4];
#pragma unroll
  for (int dt = 0; dt < 4; ++dt)
#pragma unroll
    for (int j = 0; j < 4; ++j) O[dt][j] = 0.f;
#pragma unroll
  for (int r = 0; r < 4; ++r) { m[r] = -__builtin_inff(); ell[r] = 0.f; }

  int c0 = wv * 16;
  for (int c = c0; c < c0 + 16; ++c) {
    int kb = c * 32;
    f32x4 e0v, e1v;
#pragma unroll
    for (int j = 0; j < 4; ++j) { e0v[j] = 0.f; e1v[j] = 0.f; }
    const _Float16* kp0 = Kw + (long)(kb + lo) * 64 + g * 8;
    const _Float16* kp1 = Kw + (long)(kb + 16 + lo) * 64 + g * 8;
    f16x8 kb00 = *(const f16x8*)(kp0);
    f16x8 kb01 = *(const f16x8*)(kp0 + 32);
    f16x8 kb10 = *(const f16x8*)(kp1);
    f16x8 kb11 = *(const f16x8*)(kp1 + 32);
    e0v = mf16(qa0, kb00, e0v);
    e0v = mf16(qa1, kb01, e0v);
    e1v = mf16(qa0, kb10, e1v);
    e1v = mf16(qa1, kb11, e1v);

    float scv[4], p0[4], p1[4];
#pragma unroll
    for (int r = 0; r < 4; ++r) {
      float cm = fmaxf(e0v[r], e1v[r]);
      cm = fmaxf(cm, __shfl_xor(cm, 1));
      cm = fmaxf(cm, __shfl_xor(cm, 2));
      cm = fmaxf(cm, __shfl_xor(cm, 4));
      cm = fmaxf(cm, __shfl_xor(cm, 8));
      float mn = fmaxf(m[r], cm);
      float sc = __expf(m[r] - mn);
      m[r] = mn;
      p0[r] = __expf(e0v[r] - mn);
      p1[r] = __expf(e1v[r] - mn);
      float rs = p0[r] + p1[r];
      rs += __shfl_xor(rs, 1);
      rs += __shfl_xor(rs, 2);
      rs += __shfl_xor(rs, 4);
      rs += __shfl_xor(rs, 8);
      ell[r] = ell[r] * sc + rs;
      scv[r] = sc;
    }
    int srcl = (lo >> 2) << 4;
    float t0 = __shfl(scv[0], srcl), t1 = __shfl(scv[1], srcl);
    float t2 = __shfl(scv[2], srcl), t3 = __shfl(scv[3], srcl);
    float scq = (lo & 2) ? ((lo & 1) ? t3 : t2) : ((lo & 1) ? t1 : t0);
#pragma unroll
    for (int dt = 0; dt < 4; ++dt)
#pragma unroll
      for (int j = 0; j < 4; ++j) O[dt][j] *= scq;
#pragma unroll
    for (int r = 0; r < 4; ++r) {
      Plds[ws4][g * 4 + r][lo] = (_Float16)p0[r];
      Plds[ws4][g * 4 + r][16 + lo] = (_Float16)p1[r];
    }
    f16x8 pb = *(const f16x8*)&Plds[ws4][lo][g * 8];
#pragma unroll
    for (int dt = 0; dt < 4; ++dt) {
      f16x8 va = *(const f16x8*)(Vw + (long)(dt * 16 + lo) * RS_ + R_ + kb + g * 8);
      O[dt] = mf16(va, pb, O[dt]);
    }
  }

  // ---- merge the two waves' online-softmax states
  if (wv == 1) {
#pragma unroll
    for (int dt = 0; dt < 4; ++dt)
#pragma unroll
      for (int j = 0; j < 4; ++j) OBl[p][dt * 16 + g * 4 + j][lo] = O[dt][j];
    if (lo == 0) {
#pragma unroll
      for (int r = 0; r < 4; ++r) {
        mrgM[p][g * 4 + r] = m[r];
        mrgL[p][g * 4 + r] = ell[r];
      }
    }
  }
  __syncthreads();
  if (wv == 0) {
    float sA[4], sB[4], iv[4];
#pragma unroll
    for (int r = 0; r < 4; ++r) {
      float mB = mrgM[p][g * 4 + r];
      float lB = mrgL[p][g * 4 + r];
      float m12 = fmaxf(m[r], mB);
      sA[r] = __expf(m[r] - m12);
      sB[r] = __expf(mB - m12);
      iv[r] = 1.0f / (ell[r] * sA[r] + lB * sB[r]);
    }
    int srcl = (lo >> 2) << 4;
    float a0 = __shfl(sA[0], srcl), a1 = __shfl(sA[1], srcl);
    float a2 = __shfl(sA[2], srcl), a3 = __shfl(sA[3], srcl);
    float sAq = (lo & 2) ? ((lo & 1) ? a3 : a2) : ((lo & 1) ? a1 : a0);
    float b0 = __shfl(sB[0], srcl), b1 = __shfl(sB[1], srcl);
    float b2 = __shfl(sB[2], srcl), b3 = __shfl(sB[3], srcl);
    float sBq = (lo & 2) ? ((lo & 1) ? b3 : b2) : ((lo & 1) ? b1 : b0);
    float c0v = __shfl(iv[0], srcl), c1v = __shfl(iv[1], srcl);
    float c2v = __shfl(iv[2], srcl), c3v = __shfl(iv[3], srcl);
    float ivq = (lo & 2) ? ((lo & 1) ? c3v : c2v) : ((lo & 1) ? c1v : c0v);
#pragma unroll
    for (int dt = 0; dt < 4; ++dt)
#pragma unroll
      for (int j = 0; j < 4; ++j)
        O[dt][j] = (O[dt][j] * sAq + OBl[p][dt * 16 + g * 4 + j][lo] * sBq) * ivq;
    // rules contribution (already normalized): O += Vr^T x fw
    f16x8 fb = *(const f16x8*)&fwlds[p][lo][g * 8];
#pragma unroll
    for (int dt = 0; dt < 4; ++dt) {
      f16x8 va = *(const f16x8*)(Vw + (long)(dt * 16 + lo) * RS_ + g * 8);
      O[dt] = mf16(va, fb, O[dt]);
    }
#pragma unroll
    for (int dt = 0; dt < 4; ++dt)
#pragma unroll
      for (int j = 0; j < 4; ++j) Olds[p][lo][dt * 16 + g * 4 + j] = O[dt][j];
  }
  __syncthreads();
  for (int idx = tid; idx < 2 * 16 * 64; idx += 256) {
    int pp = idx >> 10;
    int row = (idx >> 6) & 15;
    int col = idx & 63;
    int qt2 = (blockIdx.x * 2 + pp) & 63;
    AO[((long)(b * S_ + qt2 * 16 + row)) * E_ + h * 64 + col] = Olds[pp][row][col];
  }
}

// ---------------------------------------------------------------------------
// Kernel 4: output projection out[n,e] = sum_f X[n,f]*Wo[e,f] + bo[e]
// ---------------------------------------------------------------------------
__global__ __launch_bounds__(256) void out_proj(const float* __restrict__ X,
                                                const float* __restrict__ Wo,
                                                const float* __restrict__ bo,
                                                float* __restrict__ Out) {
  int blk = blockIdx.x;
  int ct = blk % 12;
  int rt = blk / 12;
  int tid = threadIdx.x;
  int ecol = tid & 63, rg = tid >> 6;

  __shared__ float Xl[16][64];
  __shared__ float Wt[64][65];

  float acc[4] = {0.f, 0.f, 0.f, 0.f};
  int e0 = ct * 64, r0 = rt * 16;
  for (int f0 = 0; f0 < E_; f0 += 64) {
    __syncthreads();
    for (int i = tid; i < 1024; i += 256) {
      int rr = i >> 6, ff = i & 63;
      Xl[rr][ff] = X[(long)(r0 + rr) * E_ + f0 + ff];
    }
    for (int i = tid; i < 4096; i += 256) {
      int ii = i >> 6, jj = i & 63;
      Wt[jj][ii] = Wo[(long)(e0 + ii) * E_ + f0 + jj];
    }
    __syncthreads();
#pragma unroll 8
    for (int f = 0; f < 64; ++f) {
      float w = Wt[f][ecol];
      acc[0] += Xl[rg * 4 + 0][f] * w;
      acc[1] += Xl[rg * 4 + 1][f] * w;
      acc[2] += Xl[rg * 4 + 2][f] * w;
      acc[3] += Xl[rg * 4 + 3][f] * w;
    }
  }
  float bias = bo[e0 + ecol];
#pragma unroll
  for (int rr = 0; rr < 4; ++rr) {
    Out[(long)(r0 + rg * 4 + rr) * E_ + e0 + ecol] = acc[rr] + bias;
  }
}

extern "C" void kernel_launch(void* const* d_in, const int* in_sizes, int n_in,
                              void* d_out, int out_size, void* d_ws, size_t ws_size,
                              hipStream_t stream) {
  const float* query = (const float*)d_in[0];
  const float* key   = (const float*)d_in[1];
  const float* value = (const float*)d_in[2];
  const float* rk    = (const float*)d_in[3];
  const float* rw    = (const float*)d_in[4];
  const float* Wq    = (const float*)d_in[5];
  const float* Wk    = (const float*)d_in[6];
  const float* Wv    = (const float*)d_in[7];
  const float* bv    = (const float*)d_in[8];
  const float* Wo    = (const float*)d_in[9];
  const float* bo    = (const float*)d_in[10];
  float* out = (float*)d_out;

  char* wsb = (char*)d_ws;
  float* AO = (float*)wsb;                                   // 6,291,456 B
  _Float16* Qh  = (_Float16*)(wsb + 6291456);                // 3,145,728 B
  _Float16* Kh  = (_Float16*)(wsb + 6291456 + 3145728);      // 3,145,728 B
  _Float16* VPT = (_Float16*)(wsb + 6291456 + 2 * 3145728);  // 3,244,032 B
  __bf16* W1b = (__bf16*)(wsb + 6291456 + 2 * 3145728 + 3244032);
  __bf16* W2b = W1b + 24576;
  float* cb = (float*)(W2b + 24576);

  prep_rules<<<384, 64, 0, stream>>>(rk, rw, W1b, W2b, cb);
  qk_proj<<<1536, 256, 0, stream>>>(query, key, Wq, Wk, Qh, Kh);
  v_proj<<<24 * 66, 256, 0, stream>>>(value, Wv, bv, VPT);
  attn_mfma<<<768, 256, 0, stream>>>(Qh, Kh, VPT, W1b, W2b, cb, AO);
  out_proj<<<128 * 12, 256, 0, stream>>>(AO, Wo, bo, out);
}

// Round 6
// 122.961 us; speedup vs baseline: 6.0543x; 2.2748x over previous
//
#include <hip/hip_runtime.h>

#define S_ 1024
#define E_ 768
#define H_ 12
#define R_ 32
#define D_ 64
#define RS_ 1056  // R_+S_

typedef _Float16 f16x8 __attribute__((ext_vector_type(8)));
typedef __bf16   bf16x8 __attribute__((ext_vector_type(8)));
typedef float    f32x4 __attribute__((ext_vector_type(4)));

__device__ __forceinline__ f32x4 mf16(f16x8 a, f16x8 b, f32x4 c) {
  return __builtin_amdgcn_mfma_f32_16x16x32_f16(a, b, c, 0, 0, 0);
}
__device__ __forceinline__ f32x4 mbf(bf16x8 a, bf16x8 b, f32x4 c) {
  return __builtin_amdgcn_mfma_f32_16x16x32_bf16(a, b, c, 0, 0, 0);
}
__device__ __forceinline__ f16x8 cvt8(float4 a, float4 b) {
  f16x8 r;
  r[0] = (_Float16)a.x; r[1] = (_Float16)a.y; r[2] = (_Float16)a.z; r[3] = (_Float16)a.w;
  r[4] = (_Float16)b.x; r[5] = (_Float16)b.y; r[6] = (_Float16)b.z; r[7] = (_Float16)b.w;
  return r;
}

// ---------------------------------------------------------------------------
// Prep: fold fuzzy-rule quadratic form into two GEMM operand matrices.
// ---------------------------------------------------------------------------
__global__ __launch_bounds__(64) void prep_rules(const float* __restrict__ RK,
                                                 const float* __restrict__ RW,
                                                 __bf16* __restrict__ W1b,
                                                 __bf16* __restrict__ W2b,
                                                 float* __restrict__ cb) {
  int hr = blockIdx.x;  // 0..383 = h*32 + r
  int d = threadIdx.x;
  long idx = (long)hr * 64 + d;
  float w = RW[idx];
  float wi = 1.0f / w;
  float w2 = wi * wi;
  float rk = RK[idx];
  W1b[idx] = (__bf16)(-w2 * (1.0f / 524288.0f));
  W2b[idx] = (__bf16)(rk * w2 * (1.0f / 4096.0f));
  float part = rk * rk * w2;
  part += __shfl_xor(part, 1);
  part += __shfl_xor(part, 2);
  part += __shfl_xor(part, 4);
  part += __shfl_xor(part, 8);
  part += __shfl_xor(part, 16);
  part += __shfl_xor(part, 32);
  if (d == 0) cb[hr] = -part * (1.0f / 128.0f);
}

// ---------------------------------------------------------------------------
// Kernel 1: per-head Q/K projections -> f16, Q pre-scaled by 8.
// ---------------------------------------------------------------------------
__global__ __launch_bounds__(256) void qk_proj(const float* __restrict__ query,
                                               const float* __restrict__ key,
                                               const float* __restrict__ Wq,
                                               const float* __restrict__ Wk,
                                               _Float16* __restrict__ Qh,
                                               _Float16* __restrict__ Kh) {
  int blk = blockIdx.x;
  int st = blk & 63;
  int h  = (blk >> 6) % H_;
  int b  = blk / (64 * H_);
  int tid = threadIdx.x;

  __shared__ float Wqt[64][65];
  __shared__ float Wkt[64][65];
  __shared__ float xq[16][64];
  __shared__ float xk[16][64];

  for (int i = tid; i < 4096; i += 256) {
    int o = i >> 6, d = i & 63;
    Wqt[d][o] = Wq[i];
    Wkt[d][o] = Wk[i];
  }
  int s0 = st * 16;
  for (int i = tid; i < 1024; i += 256) {
    int r = i >> 6, d = i & 63;
    long addr = ((long)(b * S_ + s0 + r) * E_) + h * 64 + d;
    xq[r][d] = query[addr];
    xk[r][d] = key[addr];
  }
  __syncthreads();

  int o = tid & 63;
  int rg = tid >> 6;
  for (int rr = 0; rr < 4; ++rr) {
    int r = rg * 4 + rr;
    float aq = 0.f, ak = 0.f;
#pragma unroll
    for (int d = 0; d < 64; ++d) {
      aq += xq[r][d] * Wqt[d][o];
      ak += xk[r][d] * Wkt[d][o];
    }
    long outp = ((long)((b * H_ + h) * S_) + s0 + r) * 64 + o;
    Qh[outp] = (_Float16)(aq * 8.0f);
    Kh[outp] = (_Float16)ak;
  }
}

// ---------------------------------------------------------------------------
// Kernel 2a: transpose value -> VT16[b][e][s] f16 ([2][768][1024]).
// ---------------------------------------------------------------------------
__global__ __launch_bounds__(256) void vT(const float* __restrict__ value,
                                          _Float16* __restrict__ VT) {
  __shared__ alignas(16) _Float16 Ls[64][72];
  int blk = blockIdx.x;
  int et = blk % 12;
  int st = (blk / 12) % 16;
  int b = blk / (12 * 16);
  int s0 = st * 64, e0 = et * 64;
  int tid = threadIdx.x;
  int j = tid >> 2, part = tid & 3;

  const float4* p = (const float4*)(value + ((long)(b * S_ + s0 + j)) * E_ + e0 + part * 16);
  float4 x0 = p[0], x1 = p[1], x2 = p[2], x3 = p[3];
  *(f16x8*)&Ls[j][part * 16]     = cvt8(x0, x1);
  *(f16x8*)&Ls[j][part * 16 + 8] = cvt8(x2, x3);
  __syncthreads();

  int i = tid >> 2;  // local e row
  f16x8 o0, o1;
#pragma unroll
  for (int q = 0; q < 8; ++q) o0[q] = Ls[part * 16 + q][i];
#pragma unroll
  for (int q = 0; q < 8; ++q) o1[q] = Ls[part * 16 + 8 + q][i];
  _Float16* op = VT + ((long)(b * E_ + e0 + i)) * S_ + s0 + part * 16;
  *(f16x8*)op = o0;
  *((f16x8*)op + 1) = o1;
}

// ---------------------------------------------------------------------------
// Kernel 2b: MFMA value projection. Per b: C[r,e] = sum_s Wv[r,s]*VT[b,e,s].
// Writes VPT[b, h=e/64, d=e%64, r] = C[r,e] + bv[r]   (f16).
// 64x64 tiles, K=1024 in 16 steps of 64, double-buffered LDS.
// ---------------------------------------------------------------------------
__global__ __launch_bounds__(256) void v_proj_mfma(const float* __restrict__ Wv,
                                                   const float* __restrict__ bv,
                                                   const _Float16* __restrict__ VT,
                                                   _Float16* __restrict__ VPT) {
  __shared__ alignas(16) _Float16 As[2][64][72];
  __shared__ alignas(16) _Float16 Bs[2][64][72];

  int tid = threadIdx.x;
  int blk = blockIdx.x;
  int et = blk % 12;               // head
  int rt = (blk / 12) % 17;        // r-tile (last ragged)
  int b  = blk / (12 * 17);
  int r0 = rt * 64, e0 = et * 64;
  int w = tid >> 6, l = tid & 63, lo = l & 15, g = l >> 4;
  int i = tid >> 2, part = tid & 3;

  bool rvalid = (r0 + i) < RS_;
  const float* wvp = Wv + (long)(r0 + i) * S_ + part * 16;
  const _Float16* vtp = VT + ((long)(b * E_ + e0 + i)) * S_ + part * 16;

  f32x4 acc[4];
#pragma unroll
  for (int ns = 0; ns < 4; ++ns)
#pragma unroll
    for (int q = 0; q < 4; ++q) acc[ns][q] = 0.f;

  auto STAGE = [&](int kb, int bufi) {
    float4 x0, x1, x2, x3;
    if (rvalid) {
      const float4* p = (const float4*)(wvp + kb);
      x0 = p[0]; x1 = p[1]; x2 = p[2]; x3 = p[3];
    } else {
      x0 = x1 = x2 = x3 = make_float4(0.f, 0.f, 0.f, 0.f);
    }
    *(f16x8*)&As[bufi][i][part * 16]     = cvt8(x0, x1);
    *(f16x8*)&As[bufi][i][part * 16 + 8] = cvt8(x2, x3);
    const uint4* vp4 = (const uint4*)(vtp + kb);
    uint4 b0 = vp4[0], b1 = vp4[1];
    *(uint4*)&Bs[bufi][i][part * 16]     = b0;
    *(uint4*)&Bs[bufi][i][part * 16 + 8] = b1;
  };

  STAGE(0, 0);
  __syncthreads();
  for (int k = 0; k < 16; ++k) {
    if (k < 15) STAGE((k + 1) * 64, (k + 1) & 1);
    int bi = k & 1;
#pragma unroll
    for (int kc = 0; kc < 2; ++kc) {
      f16x8 af = *(const f16x8*)&As[bi][w * 16 + lo][kc * 32 + g * 8];
#pragma unroll
      for (int ns = 0; ns < 4; ++ns) {
        f16x8 bf = *(const f16x8*)&Bs[bi][ns * 16 + lo][kc * 32 + g * 8];
        acc[ns] = mf16(af, bf, acc[ns]);
      }
    }
    __syncthreads();
  }

  // epilogue: acc[ns][reg] = C[r = r0 + w*16 + g*4 + reg][e0 + ns*16 + lo]
  float bvr[4];
#pragma unroll
  for (int reg = 0; reg < 4; ++reg) {
    int r = r0 + w * 16 + g * 4 + reg;
    bvr[reg] = (r < RS_) ? bv[r] : 0.f;
  }
  float* Ct = (float*)&As[0][0][0];  // Ct[d][rloc], stride 69
#pragma unroll
  for (int ns = 0; ns < 4; ++ns)
#pragma unroll
    for (int reg = 0; reg < 4; ++reg)
      Ct[(ns * 16 + lo) * 69 + w * 16 + g * 4 + reg] = acc[ns][reg] + bvr[reg];
  __syncthreads();

  if (r0 + part * 16 < RS_) {
    f16x8 o0, o1;
#pragma unroll
    for (int q = 0; q < 8; ++q) o0[q] = (_Float16)Ct[i * 69 + part * 16 + q];
#pragma unroll
    for (int q = 0; q < 8; ++q) o1[q] = (_Float16)Ct[i * 69 + part * 16 + 8 + q];
    _Float16* op = VPT + ((long)((b * H_ + et) * 64 + i)) * RS_ + r0 + part * 16;
    *(f16x8*)op = o0;
    *((f16x8*)op + 1) = o1;
  }
}

// ---------------------------------------------------------------------------
// Kernel 3: MFMA flash attention + fuzzy-rule branch.  AO output now f16.
// ---------------------------------------------------------------------------
__global__ __launch_bounds__(256) void attn_mfma(
    const _Float16* __restrict__ Qh, const _Float16* __restrict__ Kh,
    const _Float16* __restrict__ VPT, const __bf16* __restrict__ W1b,
    const __bf16* __restrict__ W2b, const float* __restrict__ cb,
    _Float16* __restrict__ AO) {
  __shared__ alignas(16) _Float16 Plds[4][16][40];
  __shared__ alignas(16) _Float16 fwlds[2][16][40];
  __shared__ float OBl[2][64][17];
  __shared__ float mrgM[2][16];
  __shared__ float mrgL[2][16];
  __shared__ float Olds[2][16][68];

  int tid = threadIdx.x;
  int p = tid >> 7;
  int wv = (tid >> 6) & 1;
  int l = tid & 63;
  int lo = l & 15, g = l >> 4;
  int ws4 = tid >> 6;

  int pidx = blockIdx.x * 2 + p;
  int bh = pidx >> 6;
  int qt = pidx & 63;
  int b = bh / H_, h = bh % H_;
  int s0 = qt * 16;

  const _Float16* Qw = Qh + ((long)bh * S_ + s0) * 64;
  const _Float16* Kw = Kh + (long)bh * S_ * 64;
  const _Float16* Vw = VPT + (long)bh * 64 * RS_;

  f16x8 qa0 = *(const f16x8*)(Qw + (long)lo * 64 + g * 8);
  f16x8 qa1 = *(const f16x8*)(Qw + (long)lo * 64 + 32 + g * 8);

  if (wv == 0) {
    bf16x8 qsq0, qsq1, qbf0, qbf1;
#pragma unroll
    for (int j = 0; j < 8; ++j) {
      float a0 = (float)qa0[j], a1 = (float)qa1[j];
      qbf0[j] = (__bf16)a0;
      qbf1[j] = (__bf16)a1;
      qsq0[j] = (__bf16)(a0 * a0);
      qsq1[j] = (__bf16)(a1 * a1);
    }
    f32x4 z[2];
#pragma unroll
    for (int t = 0; t < 2; ++t) {
      float cc = cb[h * R_ + t * 16 + lo];
#pragma unroll
      for (int j = 0; j < 4; ++j) z[t][j] = cc;
      const __bf16* w1p = W1b + ((long)h * R_ + t * 16 + lo) * 64;
      const __bf16* w2p = W2b + ((long)h * R_ + t * 16 + lo) * 64;
      bf16x8 b10 = *(const bf16x8*)(w1p + g * 8);
      bf16x8 b11 = *(const bf16x8*)(w1p + 32 + g * 8);
      bf16x8 b20 = *(const bf16x8*)(w2p + g * 8);
      bf16x8 b21 = *(const bf16x8*)(w2p + 32 + g * 8);
      z[t] = mbf(qsq0, b10, z[t]);
      z[t] = mbf(qsq1, b11, z[t]);
      z[t] = mbf(qbf0, b20, z[t]);
      z[t] = mbf(qbf1, b21, z[t]);
    }
#pragma unroll
    for (int r = 0; r < 4; ++r) {
      float cm = fmaxf(z[0][r], z[1][r]);
      cm = fmaxf(cm, __shfl_xor(cm, 1));
      cm = fmaxf(cm, __shfl_xor(cm, 2));
      cm = fmaxf(cm, __shfl_xor(cm, 4));
      cm = fmaxf(cm, __shfl_xor(cm, 8));
      float e0 = __expf(z[0][r] - cm);
      float e1 = __expf(z[1][r] - cm);
      float sum = e0 + e1;
      sum += __shfl_xor(sum, 1);
      sum += __shfl_xor(sum, 2);
      sum += __shfl_xor(sum, 4);
      sum += __shfl_xor(sum, 8);
      float inv = 1.0f / sum;
      fwlds[p][g * 4 + r][lo] = (_Float16)(e0 * inv);
      fwlds[p][g * 4 + r][16 + lo] = (_Float16)(e1 * inv);
    }
  }

  f32x4 O[4];
  float m[4], ell[4];
#pragma unroll
  for (int dt = 0; dt < 4; ++dt)
#pragma unroll
    for (int j = 0; j < 4; ++j) O[dt][j] = 0.f;
#pragma unroll
  for (int r = 0; r < 4; ++r) { m[r] = -__builtin_inff(); ell[r] = 0.f; }

  int c0 = wv * 16;
  for (int c = c0; c < c0 + 16; ++c) {
    int kb = c * 32;
    f32x4 e0v, e1v;
#pragma unroll
    for (int j = 0; j < 4; ++j) { e0v[j] = 0.f; e1v[j] = 0.f; }
    const _Float16* kp0 = Kw + (long)(kb + lo) * 64 + g * 8;
    const _Float16* kp1 = Kw + (long)(kb + 16 + lo) * 64 + g * 8;
    f16x8 kb00 = *(const f16x8*)(kp0);
    f16x8 kb01 = *(const f16x8*)(kp0 + 32);
    f16x8 kb10 = *(const f16x8*)(kp1);
    f16x8 kb11 = *(const f16x8*)(kp1 + 32);
    e0v = mf16(qa0, kb00, e0v);
    e0v = mf16(qa1, kb01, e0v);
    e1v = mf16(qa0, kb10, e1v);
    e1v = mf16(qa1, kb11, e1v);

    float scv[4], p0[4], p1[4];
#pragma unroll
    for (int r = 0; r < 4; ++r) {
      float cm = fmaxf(e0v[r], e1v[r]);
      cm = fmaxf(cm, __shfl_xor(cm, 1));
      cm = fmaxf(cm, __shfl_xor(cm, 2));
      cm = fmaxf(cm, __shfl_xor(cm, 4));
      cm = fmaxf(cm, __shfl_xor(cm, 8));
      float mn = fmaxf(m[r], cm);
      float sc = __expf(m[r] - mn);
      m[r] = mn;
      p0[r] = __expf(e0v[r] - mn);
      p1[r] = __expf(e1v[r] - mn);
      float rs = p0[r] + p1[r];
      rs += __shfl_xor(rs, 1);
      rs += __shfl_xor(rs, 2);
      rs += __shfl_xor(rs, 4);
      rs += __shfl_xor(rs, 8);
      ell[r] = ell[r] * sc + rs;
      scv[r] = sc;
    }
    int srcl = (lo >> 2) << 4;
    float t0 = __shfl(scv[0], srcl), t1 = __shfl(scv[1], srcl);
    float t2 = __shfl(scv[2], srcl), t3 = __shfl(scv[3], srcl);
    float scq = (lo & 2) ? ((lo & 1) ? t3 : t2) : ((lo & 1) ? t1 : t0);
#pragma unroll
    for (int dt = 0; dt < 4; ++dt)
#pragma unroll
      for (int j = 0; j < 4; ++j) O[dt][j] *= scq;
#pragma unroll
    for (int r = 0; r < 4; ++r) {
      Plds[ws4][g * 4 + r][lo] = (_Float16)p0[r];
      Plds[ws4][g * 4 + r][16 + lo] = (_Float16)p1[r];
    }
    f16x8 pb = *(const f16x8*)&Plds[ws4][lo][g * 8];
#pragma unroll
    for (int dt = 0; dt < 4; ++dt) {
      f16x8 va = *(const f16x8*)(Vw + (long)(dt * 16 + lo) * RS_ + R_ + kb + g * 8);
      O[dt] = mf16(va, pb, O[dt]);
    }
  }

  if (wv == 1) {
#pragma unroll
    for (int dt = 0; dt < 4; ++dt)
#pragma unroll
      for (int j = 0; j < 4; ++j) OBl[p][dt * 16 + g * 4 + j][lo] = O[dt][j];
    if (lo == 0) {
#pragma unroll
      for (int r = 0; r < 4; ++r) {
        mrgM[p][g * 4 + r] = m[r];
        mrgL[p][g * 4 + r] = ell[r];
      }
    }
  }
  __syncthreads();
  if (wv == 0) {
    float sA[4], sB[4], iv[4];
#pragma unroll
    for (int r = 0; r < 4; ++r) {
      float mB = mrgM[p][g * 4 + r];
      float lB = mrgL[p][g * 4 + r];
      float m12 = fmaxf(m[r], mB);
      sA[r] = __expf(m[r] - m12);
      sB[r] = __expf(mB - m12);
      iv[r] = 1.0f / (ell[r] * sA[r] + lB * sB[r]);
    }
    int srcl = (lo >> 2) << 4;
    float a0 = __shfl(sA[0], srcl), a1 = __shfl(sA[1], srcl);
    float a2 = __shfl(sA[2], srcl), a3 = __shfl(sA[3], srcl);
    float sAq = (lo & 2) ? ((lo & 1) ? a3 : a2) : ((lo & 1) ? a1 : a0);
    float b0 = __shfl(sB[0], srcl), b1 = __shfl(sB[1], srcl);
    float b2 = __shfl(sB[2], srcl), b3 = __shfl(sB[3], srcl);
    float sBq = (lo & 2) ? ((lo & 1) ? b3 : b2) : ((lo & 1) ? b1 : b0);
    float c0v = __shfl(iv[0], srcl), c1v = __shfl(iv[1], srcl);
    float c2v = __shfl(iv[2], srcl), c3v = __shfl(iv[3], srcl);
    float ivq = (lo & 2) ? ((lo & 1) ? c3v : c2v) : ((lo & 1) ? c1v : c0v);
#pragma unroll
    for (int dt = 0; dt < 4; ++dt)
#pragma unroll
      for (int j = 0; j < 4; ++j)
        O[dt][j] = (O[dt][j] * sAq + OBl[p][dt * 16 + g * 4 + j][lo] * sBq) * ivq;
    f16x8 fb = *(const f16x8*)&fwlds[p][lo][g * 8];
#pragma unroll
    for (int dt = 0; dt < 4; ++dt) {
      f16x8 va = *(const f16x8*)(Vw + (long)(dt * 16 + lo) * RS_ + g * 8);
      O[dt] = mf16(va, fb, O[dt]);
    }
#pragma unroll
    for (int dt = 0; dt < 4; ++dt)
#pragma unroll
      for (int j = 0; j < 4; ++j) Olds[p][lo][dt * 16 + g * 4 + j] = O[dt][j];
  }
  __syncthreads();
  for (int idx = tid; idx < 2 * 16 * 64; idx += 256) {
    int pp = idx >> 10;
    int row = (idx >> 6) & 15;
    int col = idx & 63;
    int qt2 = (blockIdx.x * 2 + pp) & 63;
    AO[((long)(b * S_ + qt2 * 16 + row)) * E_ + h * 64 + col] = (_Float16)Olds[pp][row][col];
  }
}

// ---------------------------------------------------------------------------
// Kernel 4: MFMA output projection. C[n,e] = sum_f AO16[n,f]*Wo[e,f] + bo[e].
// ---------------------------------------------------------------------------
__global__ __launch_bounds__(256) void out_proj_mfma(const _Float16* __restrict__ AO16,
                                                     const float* __restrict__ Wo,
                                                     const float* __restrict__ bo,
                                                     float* __restrict__ Out) {
  __shared__ alignas(16) _Float16 As[2][64][72];
  __shared__ alignas(16) _Float16 Bs[2][64][72];

  int tid = threadIdx.x;
  int blk = blockIdx.x;
  int et = blk % 12;
  int nt = blk / 12;
  int n0 = nt * 64, e0 = et * 64;
  int w = tid >> 6, l = tid & 63, lo = l & 15, g = l >> 4;
  int i = tid >> 2, part = tid & 3;

  const _Float16* aop = AO16 + (long)(n0 + i) * E_ + part * 16;
  const float* wop = Wo + (long)(e0 + i) * E_ + part * 16;

  f32x4 acc[4];
#pragma unroll
  for (int ns = 0; ns < 4; ++ns)
#pragma unroll
    for (int q = 0; q < 4; ++q) acc[ns][q] = 0.f;

  auto STAGE = [&](int kb, int bufi) {
    const uint4* ap4 = (const uint4*)(aop + kb);
    uint4 a0 = ap4[0], a1 = ap4[1];
    *(uint4*)&As[bufi][i][part * 16]     = a0;
    *(uint4*)&As[bufi][i][part * 16 + 8] = a1;
    const float4* p = (const float4*)(wop + kb);
    float4 x0 = p[0], x1 = p[1], x2 = p[2], x3 = p[3];
    *(f16x8*)&Bs[bufi][i][part * 16]     = cvt8(x0, x1);
    *(f16x8*)&Bs[bufi][i][part * 16 + 8] = cvt8(x2, x3);
  };

  STAGE(0, 0);
  __syncthreads();
  for (int k = 0; k < 12; ++k) {
    if (k < 11) STAGE((k + 1) * 64, (k + 1) & 1);
    int bi = k & 1;
#pragma unroll
    for (int kc = 0; kc < 2; ++kc) {
      f16x8 af = *(const f16x8*)&As[bi][w * 16 + lo][kc * 32 + g * 8];
#pragma unroll
      for (int ns = 0; ns < 4; ++ns) {
        f16x8 bf = *(const f16x8*)&Bs[bi][ns * 16 + lo][kc * 32 + g * 8];
        acc[ns] = mf16(af, bf, acc[ns]);
      }
    }
    __syncthreads();
  }

  // acc[ns][reg] = C[n = n0 + w*16 + g*4 + reg][e0 + ns*16 + lo]
  float* Cs = (float*)&As[0][0][0];  // Cs[n][e], stride 69
#pragma unroll
  for (int ns = 0; ns < 4; ++ns)
#pragma unroll
    for (int reg = 0; reg < 4; ++reg)
      Cs[(w * 16 + g * 4 + reg) * 69 + ns * 16 + lo] = acc[ns][reg];
  __syncthreads();

  float tmp[16];
#pragma unroll
  for (int q = 0; q < 16; ++q)
    tmp[q] = Cs[i * 69 + part * 16 + q] + bo[e0 + part * 16 + q];
  float* outp = Out + (long)(n0 + i) * E_ + e0 + part * 16;
#pragma unroll
  for (int q4 = 0; q4 < 4; ++q4)
    ((float4*)outp)[q4] = make_float4(tmp[q4 * 4], tmp[q4 * 4 + 1], tmp[q4 * 4 + 2], tmp[q4 * 4 + 3]);
}

extern "C" void kernel_launch(void* const* d_in, const int* in_sizes, int n_in,
                              void* d_out, int out_size, void* d_ws, size_t ws_size,
                              hipStream_t stream) {
  const float* query = (const float*)d_in[0];
  const float* key   = (const float*)d_in[1];
  const float* value = (const float*)d_in[2];
  const float* rk    = (const float*)d_in[3];
  const float* rw    = (const float*)d_in[4];
  const float* Wq    = (const float*)d_in[5];
  const float* Wk    = (const float*)d_in[6];
  const float* Wv    = (const float*)d_in[7];
  const float* bv    = (const float*)d_in[8];
  const float* Wo    = (const float*)d_in[9];
  const float* bo    = (const float*)d_in[10];
  float* out = (float*)d_out;

  char* wsb = (char*)d_ws;
  _Float16* Qh  = (_Float16*)(wsb);                  // 3,145,728 B
  _Float16* Kh  = (_Float16*)(wsb + 3145728);        // 3,145,728 B
  _Float16* VPT = (_Float16*)(wsb + 6291456);        // 3,244,032 B
  _Float16* VT  = (_Float16*)(wsb + 9535488);        // 3,145,728 B (aliased w/ AO16)
  _Float16* AO16 = VT;  // VT dead after v_proj_mfma; attn writes AO16 after
  __bf16* W1b = (__bf16*)(wsb + 12681216);           // 49,152 B
  __bf16* W2b = (__bf16*)(wsb + 12730368);           // 49,152 B
  float* cb   = (float*)(wsb + 12779520);            // 1,536 B

  prep_rules<<<384, 64, 0, stream>>>(rk, rw, W1b, W2b, cb);
  qk_proj<<<1536, 256, 0, stream>>>(query, key, Wq, Wk, Qh, Kh);
  vT<<<2 * 16 * 12, 256, 0, stream>>>(value, VT);
  v_proj_mfma<<<2 * 17 * 12, 256, 0, stream>>>(Wv, bv, VT, VPT);
  attn_mfma<<<768, 256, 0, stream>>>(Qh, Kh, VPT, W1b, W2b, cb, AO16);
  out_proj_mfma<<<32 * 12, 256, 0, stream>>>(AO16, Wo, bo, out);
}

// Round 7
// 102.630 us; speedup vs baseline: 7.2536x; 1.1981x over previous
//
#include <hip/hip_runtime.h>

#define S_ 1024
#define E_ 768
#define H_ 12
#define R_ 32
#define D_ 64
#define RS_ 1056  // R_+S_

typedef _Float16 f16x8 __attribute__((ext_vector_type(8)));
typedef __bf16   bf16x8 __attribute__((ext_vector_type(8)));
typedef float    f32x4 __attribute__((ext_vector_type(4)));

__device__ __forceinline__ f32x4 mf16(f16x8 a, f16x8 b, f32x4 c) {
  return __builtin_amdgcn_mfma_f32_16x16x32_f16(a, b, c, 0, 0, 0);
}
__device__ __forceinline__ f32x4 mbf(bf16x8 a, bf16x8 b, f32x4 c) {
  return __builtin_amdgcn_mfma_f32_16x16x32_bf16(a, b, c, 0, 0, 0);
}
__device__ __forceinline__ f16x8 cvt8(float4 a, float4 b) {
  f16x8 r;
  r[0] = (_Float16)a.x; r[1] = (_Float16)a.y; r[2] = (_Float16)a.z; r[3] = (_Float16)a.w;
  r[4] = (_Float16)b.x; r[5] = (_Float16)b.y; r[6] = (_Float16)b.z; r[7] = (_Float16)b.w;
  return r;
}

// ---------------------------------------------------------------------------
// Prep: fold fuzzy-rule quadratic form into two GEMM operand matrices.
// ---------------------------------------------------------------------------
__global__ __launch_bounds__(64) void prep_rules(const float* __restrict__ RK,
                                                 const float* __restrict__ RW,
                                                 __bf16* __restrict__ W1b,
                                                 __bf16* __restrict__ W2b,
                                                 float* __restrict__ cb) {
  int hr = blockIdx.x;  // 0..383 = h*32 + r
  int d = threadIdx.x;
  long idx = (long)hr * 64 + d;
  float w = RW[idx];
  float wi = 1.0f / w;
  float w2 = wi * wi;
  float rk = RK[idx];
  W1b[idx] = (__bf16)(-w2 * (1.0f / 524288.0f));
  W2b[idx] = (__bf16)(rk * w2 * (1.0f / 4096.0f));
  float part = rk * rk * w2;
  part += __shfl_xor(part, 1);
  part += __shfl_xor(part, 2);
  part += __shfl_xor(part, 4);
  part += __shfl_xor(part, 8);
  part += __shfl_xor(part, 16);
  part += __shfl_xor(part, 32);
  if (d == 0) cb[hr] = -part * (1.0f / 128.0f);
}

// ---------------------------------------------------------------------------
// Kernel 1: per-head Q/K projections via MFMA, zero LDS.
// q[s,o] = sum_d x[b,s,h*64+d] * Wq[o,d]; Q pre-scaled by 8.  f16 out.
// grid = B*H*(S/64) = 384 blocks x 4 waves; wave = 16 s-rows x 64 outputs.
// ---------------------------------------------------------------------------
__global__ __launch_bounds__(256) void qk_proj_mfma(const float* __restrict__ query,
                                                    const float* __restrict__ key,
                                                    const float* __restrict__ Wq,
                                                    const float* __restrict__ Wk,
                                                    _Float16* __restrict__ Qh,
                                                    _Float16* __restrict__ Kh) {
  int blk = blockIdx.x;
  int st = blk & 15;
  int h  = (blk >> 4) % H_;
  int b  = blk / (16 * H_);
  int tid = threadIdx.x;
  int w = tid >> 6, l = tid & 63, lo = l & 15, g = l >> 4;

  int s_in = st * 64 + w * 16 + lo;  // A-fragment row
  const float* qp = query + ((long)(b * S_) + s_in) * E_ + h * 64;
  const float* kp = key   + ((long)(b * S_) + s_in) * E_ + h * 64;
  float4 a0 = *(const float4*)(qp + g * 8);
  float4 a1 = *(const float4*)(qp + g * 8 + 4);
  float4 a2 = *(const float4*)(qp + 32 + g * 8);
  float4 a3 = *(const float4*)(qp + 32 + g * 8 + 4);
  f16x8 xq0 = cvt8(a0, a1), xq1 = cvt8(a2, a3);
  a0 = *(const float4*)(kp + g * 8);
  a1 = *(const float4*)(kp + g * 8 + 4);
  a2 = *(const float4*)(kp + 32 + g * 8);
  a3 = *(const float4*)(kp + 32 + g * 8 + 4);
  f16x8 xk0 = cvt8(a0, a1), xk1 = cvt8(a2, a3);

  f32x4 accq[4], acck[4];
#pragma unroll
  for (int ns = 0; ns < 4; ++ns)
#pragma unroll
    for (int q = 0; q < 4; ++q) { accq[ns][q] = 0.f; acck[ns][q] = 0.f; }

#pragma unroll
  for (int ns = 0; ns < 4; ++ns) {
    const float* wqp = Wq + (long)(ns * 16 + lo) * 64;
    const float* wkp = Wk + (long)(ns * 16 + lo) * 64;
    float4 b0 = *(const float4*)(wqp + g * 8);
    float4 b1 = *(const float4*)(wqp + g * 8 + 4);
    float4 b2 = *(const float4*)(wqp + 32 + g * 8);
    float4 b3 = *(const float4*)(wqp + 32 + g * 8 + 4);
    f16x8 bq0 = cvt8(b0, b1), bq1 = cvt8(b2, b3);
    b0 = *(const float4*)(wkp + g * 8);
    b1 = *(const float4*)(wkp + g * 8 + 4);
    b2 = *(const float4*)(wkp + 32 + g * 8);
    b3 = *(const float4*)(wkp + 32 + g * 8 + 4);
    f16x8 bk0 = cvt8(b0, b1), bk1 = cvt8(b2, b3);
    accq[ns] = mf16(xq0, bq0, accq[ns]);
    accq[ns] = mf16(xq1, bq1, accq[ns]);
    acck[ns] = mf16(xk0, bk0, acck[ns]);
    acck[ns] = mf16(xk1, bk1, acck[ns]);
  }

  // D layout: col o = ns*16+lo, row = g*4+reg
  long rowbase = (long)(b * H_ + h) * S_ + st * 64 + w * 16;
#pragma unroll
  for (int ns = 0; ns < 4; ++ns) {
#pragma unroll
    for (int reg = 0; reg < 4; ++reg) {
      long off = (rowbase + g * 4 + reg) * 64 + ns * 16 + lo;
      Qh[off] = (_Float16)(accq[ns][reg] * 8.0f);
      Kh[off] = (_Float16)acck[ns][reg];
    }
  }
}

// ---------------------------------------------------------------------------
// Kernel 2a: transpose value -> VT16[b][e][s] f16 ([2][768][1024]).
// ---------------------------------------------------------------------------
__global__ __launch_bounds__(256) void vT(const float* __restrict__ value,
                                          _Float16* __restrict__ VT) {
  __shared__ alignas(16) _Float16 Ls[64][72];
  int blk = blockIdx.x;
  int et = blk % 12;
  int st = (blk / 12) % 16;
  int b = blk / (12 * 16);
  int s0 = st * 64, e0 = et * 64;
  int tid = threadIdx.x;
  int j = tid >> 2, part = tid & 3;

  const float4* p = (const float4*)(value + ((long)(b * S_ + s0 + j)) * E_ + e0 + part * 16);
  float4 x0 = p[0], x1 = p[1], x2 = p[2], x3 = p[3];
  *(f16x8*)&Ls[j][part * 16]     = cvt8(x0, x1);
  *(f16x8*)&Ls[j][part * 16 + 8] = cvt8(x2, x3);
  __syncthreads();

  int i = tid >> 2;  // local e row
  f16x8 o0, o1;
#pragma unroll
  for (int q = 0; q < 8; ++q) o0[q] = Ls[part * 16 + q][i];
#pragma unroll
  for (int q = 0; q < 8; ++q) o1[q] = Ls[part * 16 + 8 + q][i];
  _Float16* op = VT + ((long)(b * E_ + e0 + i)) * S_ + s0 + part * 16;
  *(f16x8*)op = o0;
  *((f16x8*)op + 1) = o1;
}

// ---------------------------------------------------------------------------
// Kernel 2b: MFMA value projection. Per b: C[r,e] = sum_s Wv[r,s]*VT[b,e,s].
// Writes VPT[b, h=e/64, d=e%64, r] = C[r,e] + bv[r]   (f16).
// ---------------------------------------------------------------------------
__global__ __launch_bounds__(256) void v_proj_mfma(const float* __restrict__ Wv,
                                                   const float* __restrict__ bv,
                                                   const _Float16* __restrict__ VT,
                                                   _Float16* __restrict__ VPT) {
  __shared__ alignas(16) _Float16 As[2][64][72];
  __shared__ alignas(16) _Float16 Bs[2][64][72];

  int tid = threadIdx.x;
  int blk = blockIdx.x;
  int et = blk % 12;               // head
  int rt = (blk / 12) % 17;        // r-tile (last ragged)
  int b  = blk / (12 * 17);
  int r0 = rt * 64, e0 = et * 64;
  int w = tid >> 6, l = tid & 63, lo = l & 15, g = l >> 4;
  int i = tid >> 2, part = tid & 3;

  bool rvalid = (r0 + i) < RS_;
  const float* wvp = Wv + (long)(r0 + i) * S_ + part * 16;
  const _Float16* vtp = VT + ((long)(b * E_ + e0 + i)) * S_ + part * 16;

  f32x4 acc[4];
#pragma unroll
  for (int ns = 0; ns < 4; ++ns)
#pragma unroll
    for (int q = 0; q < 4; ++q) acc[ns][q] = 0.f;

  auto STAGE = [&](int kb, int bufi) {
    float4 x0, x1, x2, x3;
    if (rvalid) {
      const float4* p = (const float4*)(wvp + kb);
      x0 = p[0]; x1 = p[1]; x2 = p[2]; x3 = p[3];
    } else {
      x0 = x1 = x2 = x3 = make_float4(0.f, 0.f, 0.f, 0.f);
    }
    *(f16x8*)&As[bufi][i][part * 16]     = cvt8(x0, x1);
    *(f16x8*)&As[bufi][i][part * 16 + 8] = cvt8(x2, x3);
    const uint4* vp4 = (const uint4*)(vtp + kb);
    uint4 b0 = vp4[0], b1 = vp4[1];
    *(uint4*)&Bs[bufi][i][part * 16]     = b0;
    *(uint4*)&Bs[bufi][i][part * 16 + 8] = b1;
  };

  STAGE(0, 0);
  __syncthreads();
  for (int k = 0; k < 16; ++k) {
    if (k < 15) STAGE((k + 1) * 64, (k + 1) & 1);
    int bi = k & 1;
#pragma unroll
    for (int kc = 0; kc < 2; ++kc) {
      f16x8 af = *(const f16x8*)&As[bi][w * 16 + lo][kc * 32 + g * 8];
#pragma unroll
      for (int ns = 0; ns < 4; ++ns) {
        f16x8 bf = *(const f16x8*)&Bs[bi][ns * 16 + lo][kc * 32 + g * 8];
        acc[ns] = mf16(af, bf, acc[ns]);
      }
    }
    __syncthreads();
  }

  float bvr[4];
#pragma unroll
  for (int reg = 0; reg < 4; ++reg) {
    int r = r0 + w * 16 + g * 4 + reg;
    bvr[reg] = (r < RS_) ? bv[r] : 0.f;
  }
  float* Ct = (float*)&As[0][0][0];  // Ct[d][rloc], stride 69
#pragma unroll
  for (int ns = 0; ns < 4; ++ns)
#pragma unroll
    for (int reg = 0; reg < 4; ++reg)
      Ct[(ns * 16 + lo) * 69 + w * 16 + g * 4 + reg] = acc[ns][reg] + bvr[reg];
  __syncthreads();

  if (r0 + part * 16 < RS_) {
    f16x8 o0, o1;
#pragma unroll
    for (int q = 0; q < 8; ++q) o0[q] = (_Float16)Ct[i * 69 + part * 16 + q];
#pragma unroll
    for (int q = 0; q < 8; ++q) o1[q] = (_Float16)Ct[i * 69 + part * 16 + 8 + q];
    _Float16* op = VPT + ((long)((b * H_ + et) * 64 + i)) * RS_ + r0 + part * 16;
    *(f16x8*)op = o0;
    *((f16x8*)op + 1) = o1;
  }
}

// ---------------------------------------------------------------------------
// Kernel 3: MFMA flash attention + fuzzy-rule branch.  AO output f16.
// ---------------------------------------------------------------------------
__global__ __launch_bounds__(256) void attn_mfma(
    const _Float16* __restrict__ Qh, const _Float16* __restrict__ Kh,
    const _Float16* __restrict__ VPT, const __bf16* __restrict__ W1b,
    const __bf16* __restrict__ W2b, const float* __restrict__ cb,
    _Float16* __restrict__ AO) {
  __shared__ alignas(16) _Float16 Plds[4][16][40];
  __shared__ alignas(16) _Float16 fwlds[2][16][40];
  __shared__ float OBl[2][64][17];
  __shared__ float mrgM[2][16];
  __shared__ float mrgL[2][16];
  __shared__ float Olds[2][16][68];

  int tid = threadIdx.x;
  int p = tid >> 7;
  int wv = (tid >> 6) & 1;
  int l = tid & 63;
  int lo = l & 15, g = l >> 4;
  int ws4 = tid >> 6;

  int pidx = blockIdx.x * 2 + p;
  int bh = pidx >> 6;
  int qt = pidx & 63;
  int b = bh / H_, h = bh % H_;
  int s0 = qt * 16;

  const _Float16* Qw = Qh + ((long)bh * S_ + s0) * 64;
  const _Float16* Kw = Kh + (long)bh * S_ * 64;
  const _Float16* Vw = VPT + (long)bh * 64 * RS_;

  f16x8 qa0 = *(const f16x8*)(Qw + (long)lo * 64 + g * 8);
  f16x8 qa1 = *(const f16x8*)(Qw + (long)lo * 64 + 32 + g * 8);

  if (wv == 0) {
    bf16x8 qsq0, qsq1, qbf0, qbf1;
#pragma unroll
    for (int j = 0; j < 8; ++j) {
      float a0 = (float)qa0[j], a1 = (float)qa1[j];
      qbf0[j] = (__bf16)a0;
      qbf1[j] = (__bf16)a1;
      qsq0[j] = (__bf16)(a0 * a0);
      qsq1[j] = (__bf16)(a1 * a1);
    }
    f32x4 z[2];
#pragma unroll
    for (int t = 0; t < 2; ++t) {
      float cc = cb[h * R_ + t * 16 + lo];
#pragma unroll
      for (int j = 0; j < 4; ++j) z[t][j] = cc;
      const __bf16* w1p = W1b + ((long)h * R_ + t * 16 + lo) * 64;
      const __bf16* w2p = W2b + ((long)h * R_ + t * 16 + lo) * 64;
      bf16x8 b10 = *(const bf16x8*)(w1p + g * 8);
      bf16x8 b11 = *(const bf16x8*)(w1p + 32 + g * 8);
      bf16x8 b20 = *(const bf16x8*)(w2p + g * 8);
      bf16x8 b21 = *(const bf16x8*)(w2p + 32 + g * 8);
      z[t] = mbf(qsq0, b10, z[t]);
      z[t] = mbf(qsq1, b11, z[t]);
      z[t] = mbf(qbf0, b20, z[t]);
      z[t] = mbf(qbf1, b21, z[t]);
    }
#pragma unroll
    for (int r = 0; r < 4; ++r) {
      float cm = fmaxf(z[0][r], z[1][r]);
      cm = fmaxf(cm, __shfl_xor(cm, 1));
      cm = fmaxf(cm, __shfl_xor(cm, 2));
      cm = fmaxf(cm, __shfl_xor(cm, 4));
      cm = fmaxf(cm, __shfl_xor(cm, 8));
      float e0 = __expf(z[0][r] - cm);
      float e1 = __expf(z[1][r] - cm);
      float sum = e0 + e1;
      sum += __shfl_xor(sum, 1);
      sum += __shfl_xor(sum, 2);
      sum += __shfl_xor(sum, 4);
      sum += __shfl_xor(sum, 8);
      float inv = 1.0f / sum;
      fwlds[p][g * 4 + r][lo] = (_Float16)(e0 * inv);
      fwlds[p][g * 4 + r][16 + lo] = (_Float16)(e1 * inv);
    }
  }

  f32x4 O[4];
  float m[4], ell[4];
#pragma unroll
  for (int dt = 0; dt < 4; ++dt)
#pragma unroll
    for (int j = 0; j < 4; ++j) O[dt][j] = 0.f;
#pragma unroll
  for (int r = 0; r < 4; ++r) { m[r] = -__builtin_inff(); ell[r] = 0.f; }

  int c0 = wv * 16;
  for (int c = c0; c < c0 + 16; ++c) {
    int kb = c * 32;
    f32x4 e0v, e1v;
#pragma unroll
    for (int j = 0; j < 4; ++j) { e0v[j] = 0.f; e1v[j] = 0.f; }
    const _Float16* kp0 = Kw + (long)(kb + lo) * 64 + g * 8;
    const _Float16* kp1 = Kw + (long)(kb + 16 + lo) * 64 + g * 8;
    f16x8 kb00 = *(const f16x8*)(kp0);
    f16x8 kb01 = *(const f16x8*)(kp0 + 32);
    f16x8 kb10 = *(const f16x8*)(kp1);
    f16x8 kb11 = *(const f16x8*)(kp1 + 32);
    e0v = mf16(qa0, kb00, e0v);
    e0v = mf16(qa1, kb01, e0v);
    e1v = mf16(qa0, kb10, e1v);
    e1v = mf16(qa1, kb11, e1v);

    float scv[4], p0[4], p1[4];
#pragma unroll
    for (int r = 0; r < 4; ++r) {
      float cm = fmaxf(e0v[r], e1v[r]);
      cm = fmaxf(cm, __shfl_xor(cm, 1));
      cm = fmaxf(cm, __shfl_xor(cm, 2));
      cm = fmaxf(cm, __shfl_xor(cm, 4));
      cm = fmaxf(cm, __shfl_xor(cm, 8));
      float mn = fmaxf(m[r], cm);
      float sc = __expf(m[r] - mn);
      m[r] = mn;
      p0[r] = __expf(e0v[r] - mn);
      p1[r] = __expf(e1v[r] - mn);
      float rs = p0[r] + p1[r];
      rs += __shfl_xor(rs, 1);
      rs += __shfl_xor(rs, 2);
      rs += __shfl_xor(rs, 4);
      rs += __shfl_xor(rs, 8);
      ell[r] = ell[r] * sc + rs;
      scv[r] = sc;
    }
    int srcl = (lo >> 2) << 4;
    float t0 = __shfl(scv[0], srcl), t1 = __shfl(scv[1], srcl);
    float t2 = __shfl(scv[2], srcl), t3 = __shfl(scv[3], srcl);
    float scq = (lo & 2) ? ((lo & 1) ? t3 : t2) : ((lo & 1) ? t1 : t0);
#pragma unroll
    for (int dt = 0; dt < 4; ++dt)
#pragma unroll
      for (int j = 0; j < 4; ++j) O[dt][j] *= scq;
#pragma unroll
    for (int r = 0; r < 4; ++r) {
      Plds[ws4][g * 4 + r][lo] = (_Float16)p0[r];
      Plds[ws4][g * 4 + r][16 + lo] = (_Float16)p1[r];
    }
    f16x8 pb = *(const f16x8*)&Plds[ws4][lo][g * 8];
#pragma unroll
    for (int dt = 0; dt < 4; ++dt) {
      f16x8 va = *(const f16x8*)(Vw + (long)(dt * 16 + lo) * RS_ + R_ + kb + g * 8);
      O[dt] = mf16(va, pb, O[dt]);
    }
  }

  if (wv == 1) {
#pragma unroll
    for (int dt = 0; dt < 4; ++dt)
#pragma unroll
      for (int j = 0; j < 4; ++j) OBl[p][dt * 16 + g * 4 + j][lo] = O[dt][j];
    if (lo == 0) {
#pragma unroll
      for (int r = 0; r < 4; ++r) {
        mrgM[p][g * 4 + r] = m[r];
        mrgL[p][g * 4 + r] = ell[r];
      }
    }
  }
  __syncthreads();
  if (wv == 0) {
    float sA[4], sB[4], iv[4];
#pragma unroll
    for (int r = 0; r < 4; ++r) {
      float mB = mrgM[p][g * 4 + r];
      float lB = mrgL[p][g * 4 + r];
      float m12 = fmaxf(m[r], mB);
      sA[r] = __expf(m[r] - m12);
      sB[r] = __expf(mB - m12);
      iv[r] = 1.0f / (ell[r] * sA[r] + lB * sB[r]);
    }
    int srcl = (lo >> 2) << 4;
    float a0 = __shfl(sA[0], srcl), a1 = __shfl(sA[1], srcl);
    float a2 = __shfl(sA[2], srcl), a3 = __shfl(sA[3], srcl);
    float sAq = (lo & 2) ? ((lo & 1) ? a3 : a2) : ((lo & 1) ? a1 : a0);
    float b0 = __shfl(sB[0], srcl), b1 = __shfl(sB[1], srcl);
    float b2 = __shfl(sB[2], srcl), b3 = __shfl(sB[3], srcl);
    float sBq = (lo & 2) ? ((lo & 1) ? b3 : b2) : ((lo & 1) ? b1 : b0);
    float c0v = __shfl(iv[0], srcl), c1v = __shfl(iv[1], srcl);
    float c2v = __shfl(iv[2], srcl), c3v = __shfl(iv[3], srcl);
    float ivq = (lo & 2) ? ((lo & 1) ? c3v : c2v) : ((lo & 1) ? c1v : c0v);
#pragma unroll
    for (int dt = 0; dt < 4; ++dt)
#pragma unroll
      for (int j = 0; j < 4; ++j)
        O[dt][j] = (O[dt][j] * sAq + OBl[p][dt * 16 + g * 4 + j][lo] * sBq) * ivq;
    f16x8 fb = *(const f16x8*)&fwlds[p][lo][g * 8];
#pragma unroll
    for (int dt = 0; dt < 4; ++dt) {
      f16x8 va = *(const f16x8*)(Vw + (long)(dt * 16 + lo) * RS_ + g * 8);
      O[dt] = mf16(va, fb, O[dt]);
    }
#pragma unroll
    for (int dt = 0; dt < 4; ++dt)
#pragma unroll
      for (int j = 0; j < 4; ++j) Olds[p][lo][dt * 16 + g * 4 + j] = O[dt][j];
  }
  __syncthreads();
  for (int idx = tid; idx < 2 * 16 * 64; idx += 256) {
    int pp = idx >> 10;
    int row = (idx >> 6) & 15;
    int col = idx & 63;
    int qt2 = (blockIdx.x * 2 + pp) & 63;
    AO[((long)(b * S_ + qt2 * 16 + row)) * E_ + h * 64 + col] = (_Float16)Olds[pp][row][col];
  }
}

// ---------------------------------------------------------------------------
// Kernel 4: MFMA output projection. C[n,e] = sum_f AO16[n,f]*Wo[e,f] + bo[e].
// ---------------------------------------------------------------------------
__global__ __launch_bounds__(256) void out_proj_mfma(const _Float16* __restrict__ AO16,
                                                     const float* __restrict__ Wo,
                                                     const float* __restrict__ bo,
                                                     float* __restrict__ Out) {
  __shared__ alignas(16) _Float16 As[2][64][72];
  __shared__ alignas(16) _Float16 Bs[2][64][72];

  int tid = threadIdx.x;
  int blk = blockIdx.x;
  int et = blk % 12;
  int nt = blk / 12;
  int n0 = nt * 64, e0 = et * 64;
  int w = tid >> 6, l = tid & 63, lo = l & 15, g = l >> 4;
  int i = tid >> 2, part = tid & 3;

  const _Float16* aop = AO16 + (long)(n0 + i) * E_ + part * 16;
  const float* wop = Wo + (long)(e0 + i) * E_ + part * 16;

  f32x4 acc[4];
#pragma unroll
  for (int ns = 0; ns < 4; ++ns)
#pragma unroll
    for (int q = 0; q < 4; ++q) acc[ns][q] = 0.f;

  auto STAGE = [&](int kb, int bufi) {
    const uint4* ap4 = (const uint4*)(aop + kb);
    uint4 a0 = ap4[0], a1 = ap4[1];
    *(uint4*)&As[bufi][i][part * 16]     = a0;
    *(uint4*)&As[bufi][i][part * 16 + 8] = a1;
    const float4* p = (const float4*)(wop + kb);
    float4 x0 = p[0], x1 = p[1], x2 = p[2], x3 = p[3];
    *(f16x8*)&Bs[bufi][i][part * 16]     = cvt8(x0, x1);
    *(f16x8*)&Bs[bufi][i][part * 16 + 8] = cvt8(x2, x3);
  };

  STAGE(0, 0);
  __syncthreads();
  for (int k = 0; k < 12; ++k) {
    if (k < 11) STAGE((k + 1) * 64, (k + 1) & 1);
    int bi = k & 1;
#pragma unroll
    for (int kc = 0; kc < 2; ++kc) {
      f16x8 af = *(const f16x8*)&As[bi][w * 16 + lo][kc * 32 + g * 8];
#pragma unroll
      for (int ns = 0; ns < 4; ++ns) {
        f16x8 bf = *(const f16x8*)&Bs[bi][ns * 16 + lo][kc * 32 + g * 8];
        acc[ns] = mf16(af, bf, acc[ns]);
      }
    }
    __syncthreads();
  }

  float* Cs = (float*)&As[0][0][0];  // Cs[n][e], stride 69
#pragma unroll
  for (int ns = 0; ns < 4; ++ns)
#pragma unroll
    for (int reg = 0; reg < 4; ++reg)
      Cs[(w * 16 + g * 4 + reg) * 69 + ns * 16 + lo] = acc[ns][reg];
  __syncthreads();

  float tmp[16];
#pragma unroll
  for (int q = 0; q < 16; ++q)
    tmp[q] = Cs[i * 69 + part * 16 + q] + bo[e0 + part * 16 + q];
  float* outp = Out + (long)(n0 + i) * E_ + e0 + part * 16;
#pragma unroll
  for (int q4 = 0; q4 < 4; ++q4)
    ((float4*)outp)[q4] = make_float4(tmp[q4 * 4], tmp[q4 * 4 + 1], tmp[q4 * 4 + 2], tmp[q4 * 4 + 3]);
}

extern "C" void kernel_launch(void* const* d_in, const int* in_sizes, int n_in,
                              void* d_out, int out_size, void* d_ws, size_t ws_size,
                              hipStream_t stream) {
  const float* query = (const float*)d_in[0];
  const float* key   = (const float*)d_in[1];
  const float* value = (const float*)d_in[2];
  const float* rk    = (const float*)d_in[3];
  const float* rw    = (const float*)d_in[4];
  const float* Wq    = (const float*)d_in[5];
  const float* Wk    = (const float*)d_in[6];
  const float* Wv    = (const float*)d_in[7];
  const float* bv    = (const float*)d_in[8];
  const float* Wo    = (const float*)d_in[9];
  const float* bo    = (const float*)d_in[10];
  float* out = (float*)d_out;

  char* wsb = (char*)d_ws;
  _Float16* Qh  = (_Float16*)(wsb);                  // 3,145,728 B
  _Float16* Kh  = (_Float16*)(wsb + 3145728);        // 3,145,728 B
  _Float16* VPT = (_Float16*)(wsb + 6291456);        // 3,244,032 B
  _Float16* VT  = (_Float16*)(wsb + 9535488);        // 3,145,728 B (aliased w/ AO16)
  _Float16* AO16 = VT;  // VT dead after v_proj_mfma; attn writes AO16 after
  __bf16* W1b = (__bf16*)(wsb + 12681216);           // 49,152 B
  __bf16* W2b = (__bf16*)(wsb + 12730368);           // 49,152 B
  float* cb   = (float*)(wsb + 12779520);            // 1,536 B

  prep_rules<<<384, 64, 0, stream>>>(rk, rw, W1b, W2b, cb);
  qk_proj_mfma<<<384, 256, 0, stream>>>(query, key, Wq, Wk, Qh, Kh);
  vT<<<2 * 16 * 12, 256, 0, stream>>>(value, VT);
  v_proj_mfma<<<2 * 17 * 12, 256, 0, stream>>>(Wv, bv, VT, VPT);
  attn_mfma<<<768, 256, 0, stream>>>(Qh, Kh, VPT, W1b, W2b, cb, AO16);
  out_proj_mfma<<<32 * 12, 256, 0, stream>>>(AO16, Wo, bo, out);
}

// Round 8
// 101.215 us; speedup vs baseline: 7.3550x; 1.0140x over previous
//
#include <hip/hip_runtime.h>

#define S_ 1024
#define E_ 768
#define H_ 12
#define R_ 32
#define D_ 64
#define RS_ 1056  // R_+S_

typedef _Float16 f16x8 __attribute__((ext_vector_type(8)));
typedef __bf16   bf16x8 __attribute__((ext_vector_type(8)));
typedef float    f32x4 __attribute__((ext_vector_type(4)));

__device__ __forceinline__ f32x4 mf16(f16x8 a, f16x8 b, f32x4 c) {
  return __builtin_amdgcn_mfma_f32_16x16x32_f16(a, b, c, 0, 0, 0);
}
__device__ __forceinline__ f32x4 mbf(bf16x8 a, bf16x8 b, f32x4 c) {
  return __builtin_amdgcn_mfma_f32_16x16x32_bf16(a, b, c, 0, 0, 0);
}
__device__ __forceinline__ f16x8 cvt8(float4 a, float4 b) {
  f16x8 r;
  r[0] = (_Float16)a.x; r[1] = (_Float16)a.y; r[2] = (_Float16)a.z; r[3] = (_Float16)a.w;
  r[4] = (_Float16)b.x; r[5] = (_Float16)b.y; r[6] = (_Float16)b.z; r[7] = (_Float16)b.w;
  return r;
}

// ---------------------------------------------------------------------------
// Prep: fold fuzzy-rule quadratic form into two GEMM operand matrices.
// ---------------------------------------------------------------------------
__global__ __launch_bounds__(64) void prep_rules(const float* __restrict__ RK,
                                                 const float* __restrict__ RW,
                                                 __bf16* __restrict__ W1b,
                                                 __bf16* __restrict__ W2b,
                                                 float* __restrict__ cb) {
  int hr = blockIdx.x;  // 0..383 = h*32 + r
  int d = threadIdx.x;
  long idx = (long)hr * 64 + d;
  float w = RW[idx];
  float wi = 1.0f / w;
  float w2 = wi * wi;
  float rk = RK[idx];
  W1b[idx] = (__bf16)(-w2 * (1.0f / 524288.0f));
  W2b[idx] = (__bf16)(rk * w2 * (1.0f / 4096.0f));
  float part = rk * rk * w2;
  part += __shfl_xor(part, 1);
  part += __shfl_xor(part, 2);
  part += __shfl_xor(part, 4);
  part += __shfl_xor(part, 8);
  part += __shfl_xor(part, 16);
  part += __shfl_xor(part, 32);
  if (d == 0) cb[hr] = -part * (1.0f / 128.0f);
}

// ---------------------------------------------------------------------------
// Kernel 1: per-head Q/K projections via MFMA, zero LDS.
// ---------------------------------------------------------------------------
__global__ __launch_bounds__(256) void qk_proj_mfma(const float* __restrict__ query,
                                                    const float* __restrict__ key,
                                                    const float* __restrict__ Wq,
                                                    const float* __restrict__ Wk,
                                                    _Float16* __restrict__ Qh,
                                                    _Float16* __restrict__ Kh) {
  int blk = blockIdx.x;
  int st = blk & 15;
  int h  = (blk >> 4) % H_;
  int b  = blk / (16 * H_);
  int tid = threadIdx.x;
  int w = tid >> 6, l = tid & 63, lo = l & 15, g = l >> 4;

  int s_in = st * 64 + w * 16 + lo;
  const float* qp = query + ((long)(b * S_) + s_in) * E_ + h * 64;
  const float* kp = key   + ((long)(b * S_) + s_in) * E_ + h * 64;
  float4 a0 = *(const float4*)(qp + g * 8);
  float4 a1 = *(const float4*)(qp + g * 8 + 4);
  float4 a2 = *(const float4*)(qp + 32 + g * 8);
  float4 a3 = *(const float4*)(qp + 32 + g * 8 + 4);
  f16x8 xq0 = cvt8(a0, a1), xq1 = cvt8(a2, a3);
  a0 = *(const float4*)(kp + g * 8);
  a1 = *(const float4*)(kp + g * 8 + 4);
  a2 = *(const float4*)(kp + 32 + g * 8);
  a3 = *(const float4*)(kp + 32 + g * 8 + 4);
  f16x8 xk0 = cvt8(a0, a1), xk1 = cvt8(a2, a3);

  f32x4 accq[4], acck[4];
#pragma unroll
  for (int ns = 0; ns < 4; ++ns)
#pragma unroll
    for (int q = 0; q < 4; ++q) { accq[ns][q] = 0.f; acck[ns][q] = 0.f; }

#pragma unroll
  for (int ns = 0; ns < 4; ++ns) {
    const float* wqp = Wq + (long)(ns * 16 + lo) * 64;
    const float* wkp = Wk + (long)(ns * 16 + lo) * 64;
    float4 b0 = *(const float4*)(wqp + g * 8);
    float4 b1 = *(const float4*)(wqp + g * 8 + 4);
    float4 b2 = *(const float4*)(wqp + 32 + g * 8);
    float4 b3 = *(const float4*)(wqp + 32 + g * 8 + 4);
    f16x8 bq0 = cvt8(b0, b1), bq1 = cvt8(b2, b3);
    b0 = *(const float4*)(wkp + g * 8);
    b1 = *(const float4*)(wkp + g * 8 + 4);
    b2 = *(const float4*)(wkp + 32 + g * 8);
    b3 = *(const float4*)(wkp + 32 + g * 8 + 4);
    f16x8 bk0 = cvt8(b0, b1), bk1 = cvt8(b2, b3);
    accq[ns] = mf16(xq0, bq0, accq[ns]);
    accq[ns] = mf16(xq1, bq1, accq[ns]);
    acck[ns] = mf16(xk0, bk0, acck[ns]);
    acck[ns] = mf16(xk1, bk1, acck[ns]);
  }

  long rowbase = (long)(b * H_ + h) * S_ + st * 64 + w * 16;
#pragma unroll
  for (int ns = 0; ns < 4; ++ns) {
#pragma unroll
    for (int reg = 0; reg < 4; ++reg) {
      long off = (rowbase + g * 4 + reg) * 64 + ns * 16 + lo;
      Qh[off] = (_Float16)(accq[ns][reg] * 8.0f);
      Kh[off] = (_Float16)acck[ns][reg];
    }
  }
}

// ---------------------------------------------------------------------------
// Kernel 2a: transpose value -> VT16[b][e][s] f16 ([2][768][1024]).
// ---------------------------------------------------------------------------
__global__ __launch_bounds__(256) void vT(const float* __restrict__ value,
                                          _Float16* __restrict__ VT) {
  __shared__ alignas(16) _Float16 Ls[64][72];
  int blk = blockIdx.x;
  int et = blk % 12;
  int st = (blk / 12) % 16;
  int b = blk / (12 * 16);
  int s0 = st * 64, e0 = et * 64;
  int tid = threadIdx.x;
  int j = tid >> 2, part = tid & 3;

  const float4* p = (const float4*)(value + ((long)(b * S_ + s0 + j)) * E_ + e0 + part * 16);
  float4 x0 = p[0], x1 = p[1], x2 = p[2], x3 = p[3];
  *(f16x8*)&Ls[j][part * 16]     = cvt8(x0, x1);
  *(f16x8*)&Ls[j][part * 16 + 8] = cvt8(x2, x3);
  __syncthreads();

  int i = tid >> 2;
  f16x8 o0, o1;
#pragma unroll
  for (int q = 0; q < 8; ++q) o0[q] = Ls[part * 16 + q][i];
#pragma unroll
  for (int q = 0; q < 8; ++q) o1[q] = Ls[part * 16 + 8 + q][i];
  _Float16* op = VT + ((long)(b * E_ + e0 + i)) * S_ + s0 + part * 16;
  *(f16x8*)op = o0;
  *((f16x8*)op + 1) = o1;
}

// ---------------------------------------------------------------------------
// Kernel 2b: MFMA value projection -> VPT[b,h,d,r] f16.
// ---------------------------------------------------------------------------
__global__ __launch_bounds__(256) void v_proj_mfma(const float* __restrict__ Wv,
                                                   const float* __restrict__ bv,
                                                   const _Float16* __restrict__ VT,
                                                   _Float16* __restrict__ VPT) {
  __shared__ alignas(16) _Float16 As[2][64][72];
  __shared__ alignas(16) _Float16 Bs[2][64][72];

  int tid = threadIdx.x;
  int blk = blockIdx.x;
  int et = blk % 12;
  int rt = (blk / 12) % 17;
  int b  = blk / (12 * 17);
  int r0 = rt * 64, e0 = et * 64;
  int w = tid >> 6, l = tid & 63, lo = l & 15, g = l >> 4;
  int i = tid >> 2, part = tid & 3;

  bool rvalid = (r0 + i) < RS_;
  const float* wvp = Wv + (long)(r0 + i) * S_ + part * 16;
  const _Float16* vtp = VT + ((long)(b * E_ + e0 + i)) * S_ + part * 16;

  f32x4 acc[4];
#pragma unroll
  for (int ns = 0; ns < 4; ++ns)
#pragma unroll
    for (int q = 0; q < 4; ++q) acc[ns][q] = 0.f;

  auto STAGE = [&](int kb, int bufi) {
    float4 x0, x1, x2, x3;
    if (rvalid) {
      const float4* p = (const float4*)(wvp + kb);
      x0 = p[0]; x1 = p[1]; x2 = p[2]; x3 = p[3];
    } else {
      x0 = x1 = x2 = x3 = make_float4(0.f, 0.f, 0.f, 0.f);
    }
    *(f16x8*)&As[bufi][i][part * 16]     = cvt8(x0, x1);
    *(f16x8*)&As[bufi][i][part * 16 + 8] = cvt8(x2, x3);
    const uint4* vp4 = (const uint4*)(vtp + kb);
    uint4 b0 = vp4[0], b1 = vp4[1];
    *(uint4*)&Bs[bufi][i][part * 16]     = b0;
    *(uint4*)&Bs[bufi][i][part * 16 + 8] = b1;
  };

  STAGE(0, 0);
  __syncthreads();
  for (int k = 0; k < 16; ++k) {
    if (k < 15) STAGE((k + 1) * 64, (k + 1) & 1);
    int bi = k & 1;
#pragma unroll
    for (int kc = 0; kc < 2; ++kc) {
      f16x8 af = *(const f16x8*)&As[bi][w * 16 + lo][kc * 32 + g * 8];
#pragma unroll
      for (int ns = 0; ns < 4; ++ns) {
        f16x8 bf = *(const f16x8*)&Bs[bi][ns * 16 + lo][kc * 32 + g * 8];
        acc[ns] = mf16(af, bf, acc[ns]);
      }
    }
    __syncthreads();
  }

  float bvr[4];
#pragma unroll
  for (int reg = 0; reg < 4; ++reg) {
    int r = r0 + w * 16 + g * 4 + reg;
    bvr[reg] = (r < RS_) ? bv[r] : 0.f;
  }
  float* Ct = (float*)&As[0][0][0];  // Ct[d][rloc], stride 69
#pragma unroll
  for (int ns = 0; ns < 4; ++ns)
#pragma unroll
    for (int reg = 0; reg < 4; ++reg)
      Ct[(ns * 16 + lo) * 69 + w * 16 + g * 4 + reg] = acc[ns][reg] + bvr[reg];
  __syncthreads();

  if (r0 + part * 16 < RS_) {
    f16x8 o0, o1;
#pragma unroll
    for (int q = 0; q < 8; ++q) o0[q] = (_Float16)Ct[i * 69 + part * 16 + q];
#pragma unroll
    for (int q = 0; q < 8; ++q) o1[q] = (_Float16)Ct[i * 69 + part * 16 + 8 + q];
    _Float16* op = VPT + ((long)((b * H_ + et) * 64 + i)) * RS_ + r0 + part * 16;
    *(f16x8*)op = o0;
    *((f16x8*)op + 1) = o1;
  }
}

// ---------------------------------------------------------------------------
// Kernel 3: MFMA flash attention, SWAPPED QK^T (keys in regs, q in lanes).
// Per-lane online softmax with defer-max (THR=8). 2-wave key split + merge.
// ---------------------------------------------------------------------------
__global__ __launch_bounds__(256) void attn_mfma(
    const _Float16* __restrict__ Qh, const _Float16* __restrict__ Kh,
    const _Float16* __restrict__ VPT, const __bf16* __restrict__ W1b,
    const __bf16* __restrict__ W2b, const float* __restrict__ cb,
    _Float16* __restrict__ AO) {
  __shared__ alignas(16) _Float16 Plds[4][16][40];   // [wave][q=lo][key]
  __shared__ alignas(16) _Float16 fwlds[2][16][40];  // [pair][q=lo][rule]
  __shared__ float OBl[2][64][17];
  __shared__ float mrgM[2][16];
  __shared__ float mrgL[2][16];
  __shared__ float Olds[2][16][68];

  int tid = threadIdx.x;
  int p = tid >> 7;
  int wv = (tid >> 6) & 1;
  int l = tid & 63;
  int lo = l & 15, g = l >> 4;
  int ws4 = tid >> 6;

  int pidx = blockIdx.x * 2 + p;
  int bh = pidx >> 6;
  int qt = pidx & 63;
  int b = bh / H_, h = bh % H_;
  int s0 = qt * 16;

  const _Float16* Qw = Qh + ((long)bh * S_ + s0) * 64;
  const _Float16* Kw = Kh + (long)bh * S_ * 64;
  const _Float16* Vw = VPT + (long)bh * 64 * RS_;

  // Q as B-fragment: row = q = lo, k-slice g*8
  f16x8 qa0 = *(const f16x8*)(Qw + (long)lo * 64 + g * 8);
  f16x8 qa1 = *(const f16x8*)(Qw + (long)lo * 64 + 32 + g * 8);

  // ---- fuzzy branch (wave 0 of pair): swapped -> rule = g*4+reg, q = lo
  if (wv == 0) {
    bf16x8 qsq0, qsq1, qbf0, qbf1;
#pragma unroll
    for (int j = 0; j < 8; ++j) {
      float a0 = (float)qa0[j], a1 = (float)qa1[j];
      qbf0[j] = (__bf16)a0;
      qbf1[j] = (__bf16)a1;
      qsq0[j] = (__bf16)(a0 * a0);
      qsq1[j] = (__bf16)(a1 * a1);
    }
    f32x4 z[2];
#pragma unroll
    for (int t = 0; t < 2; ++t) {
#pragma unroll
      for (int j = 0; j < 4; ++j) z[t][j] = cb[h * R_ + t * 16 + g * 4 + j];
      const __bf16* w1p = W1b + ((long)h * R_ + t * 16 + lo) * 64;
      const __bf16* w2p = W2b + ((long)h * R_ + t * 16 + lo) * 64;
      bf16x8 b10 = *(const bf16x8*)(w1p + g * 8);
      bf16x8 b11 = *(const bf16x8*)(w1p + 32 + g * 8);
      bf16x8 b20 = *(const bf16x8*)(w2p + g * 8);
      bf16x8 b21 = *(const bf16x8*)(w2p + 32 + g * 8);
      z[t] = mbf(b10, qsq0, z[t]);   // A = rules, B = q
      z[t] = mbf(b11, qsq1, z[t]);
      z[t] = mbf(b20, qbf0, z[t]);
      z[t] = mbf(b21, qbf1, z[t]);
    }
    // per-lane softmax over 8 rules + cross-g reduce
    float zm = z[0][0];
#pragma unroll
    for (int j = 1; j < 4; ++j) zm = fmaxf(zm, z[0][j]);
#pragma unroll
    for (int j = 0; j < 4; ++j) zm = fmaxf(zm, z[1][j]);
    zm = fmaxf(zm, __shfl_xor(zm, 16));
    zm = fmaxf(zm, __shfl_xor(zm, 32));
    float ez[2][4], zsum = 0.f;
#pragma unroll
    for (int t = 0; t < 2; ++t)
#pragma unroll
      for (int j = 0; j < 4; ++j) { ez[t][j] = __expf(z[t][j] - zm); zsum += ez[t][j]; }
    zsum += __shfl_xor(zsum, 16);
    zsum += __shfl_xor(zsum, 32);
    float zin = 1.0f / zsum;
#pragma unroll
    for (int t = 0; t < 2; ++t)
#pragma unroll
      for (int j = 0; j < 4; ++j)
        fwlds[p][lo][t * 16 + g * 4 + j] = (_Float16)(ez[t][j] * zin);
  }

  // ---- flash key loop: 16 chunks of 32 keys (wv selects key half)
  f32x4 O[4];
#pragma unroll
  for (int dt = 0; dt < 4; ++dt)
#pragma unroll
    for (int j = 0; j < 4; ++j) O[dt][j] = 0.f;
  float m = -__builtin_inff();
  float ellp = 0.f;

  int kb0 = wv * 512;
  const _Float16* kp0 = Kw + (long)(kb0 + lo) * 64 + g * 8;
  const _Float16* kp1 = Kw + (long)(kb0 + 16 + lo) * 64 + g * 8;
  f16x8 kf00 = *(const f16x8*)(kp0);
  f16x8 kf01 = *(const f16x8*)(kp0 + 32);
  f16x8 kf10 = *(const f16x8*)(kp1);
  f16x8 kf11 = *(const f16x8*)(kp1 + 32);

  for (int c = 0; c < 16; ++c) {
    int kb = kb0 + c * 32;
    f16x8 nf00, nf01, nf10, nf11;
    if (c < 15) {  // prefetch next chunk's K fragments
      const _Float16* np0 = Kw + (long)(kb + 32 + lo) * 64 + g * 8;
      const _Float16* np1 = Kw + (long)(kb + 48 + lo) * 64 + g * 8;
      nf00 = *(const f16x8*)(np0);
      nf01 = *(const f16x8*)(np0 + 32);
      nf10 = *(const f16x8*)(np1);
      nf11 = *(const f16x8*)(np1 + 32);
    }
    f32x4 e0, e1;
#pragma unroll
    for (int j = 0; j < 4; ++j) { e0[j] = 0.f; e1[j] = 0.f; }
    e0 = mf16(kf00, qa0, e0);  // A = K rows, B = Q -> e0[j]: key kb+g*4+j, q=lo
    e0 = mf16(kf01, qa1, e0);
    e1 = mf16(kf10, qa0, e1);  // keys kb+16+g*4+j
    e1 = mf16(kf11, qa1, e1);

    float pmax = e0[0];
#pragma unroll
    for (int j = 1; j < 4; ++j) pmax = fmaxf(pmax, e0[j]);
#pragma unroll
    for (int j = 0; j < 4; ++j) pmax = fmaxf(pmax, e1[j]);
    pmax = fmaxf(pmax, __shfl_xor(pmax, 16));
    pmax = fmaxf(pmax, __shfl_xor(pmax, 32));
    if (__any(pmax > m + 8.0f)) {  // defer-max: rescale only when needed
      float mn = fmaxf(m, pmax);
      float sc = __expf(m - mn);
      m = mn;
      ellp *= sc;
#pragma unroll
      for (int dt = 0; dt < 4; ++dt)
#pragma unroll
        for (int j = 0; j < 4; ++j) O[dt][j] *= sc;
    }
    float p0[4], p1[4], s8 = 0.f;
#pragma unroll
    for (int j = 0; j < 4; ++j) {
      p0[j] = __expf(e0[j] - m);
      p1[j] = __expf(e1[j] - m);
      s8 += p0[j] + p1[j];
    }
    ellp += s8;
#pragma unroll
    for (int j = 0; j < 4; ++j) {
      Plds[ws4][lo][g * 4 + j] = (_Float16)p0[j];
      Plds[ws4][lo][16 + g * 4 + j] = (_Float16)p1[j];
    }
    f16x8 pb = *(const f16x8*)&Plds[ws4][lo][g * 8];  // B-frag: row q=lo, k=keys
#pragma unroll
    for (int dt = 0; dt < 4; ++dt) {
      f16x8 va = *(const f16x8*)(Vw + (long)(dt * 16 + lo) * RS_ + R_ + kb + g * 8);
      O[dt] = mf16(va, pb, O[dt]);
    }
    kf00 = nf00; kf01 = nf01; kf10 = nf10; kf11 = nf11;
  }

  // final ell: cross-g reduce (identical across g afterwards)
  float ell = ellp;
  ell += __shfl_xor(ell, 16);
  ell += __shfl_xor(ell, 32);

  // ---- merge the two waves' states (all per-lane, q = lo)
  if (wv == 1) {
#pragma unroll
    for (int dt = 0; dt < 4; ++dt)
#pragma unroll
      for (int j = 0; j < 4; ++j) OBl[p][dt * 16 + g * 4 + j][lo] = O[dt][j];
    if (l < 16) {
      mrgM[p][l] = m;
      mrgL[p][l] = ell;
    }
  }
  __syncthreads();
  if (wv == 0) {
    float mB = mrgM[p][lo];
    float lB = mrgL[p][lo];
    float m12 = fmaxf(m, mB);
    float sA = __expf(m - m12);
    float sB = __expf(mB - m12);
    float iv = 1.0f / (ell * sA + lB * sB);
    float fA = sA * iv, fB = sB * iv;
#pragma unroll
    for (int dt = 0; dt < 4; ++dt)
#pragma unroll
      for (int j = 0; j < 4; ++j)
        O[dt][j] = O[dt][j] * fA + OBl[p][dt * 16 + g * 4 + j][lo] * fB;
    // rules contribution (already normalized)
    f16x8 fb = *(const f16x8*)&fwlds[p][lo][g * 8];
#pragma unroll
    for (int dt = 0; dt < 4; ++dt) {
      f16x8 va = *(const f16x8*)(Vw + (long)(dt * 16 + lo) * RS_ + g * 8);
      O[dt] = mf16(va, fb, O[dt]);
    }
#pragma unroll
    for (int dt = 0; dt < 4; ++dt)
#pragma unroll
      for (int j = 0; j < 4; ++j) Olds[p][lo][dt * 16 + g * 4 + j] = O[dt][j];
  }
  __syncthreads();
  for (int idx = tid; idx < 2 * 16 * 64; idx += 256) {
    int pp = idx >> 10;
    int row = (idx >> 6) & 15;
    int col = idx & 63;
    int qt2 = (blockIdx.x * 2 + pp) & 63;
    AO[((long)(b * S_ + qt2 * 16 + row)) * E_ + h * 64 + col] = (_Float16)Olds[pp][row][col];
  }
}

// ---------------------------------------------------------------------------
// Kernel 4: MFMA output projection. C[n,e] = sum_f AO16[n,f]*Wo[e,f] + bo[e].
// ---------------------------------------------------------------------------
__global__ __launch_bounds__(256) void out_proj_mfma(const _Float16* __restrict__ AO16,
                                                     const float* __restrict__ Wo,
                                                     const float* __restrict__ bo,
                                                     float* __restrict__ Out) {
  __shared__ alignas(16) _Float16 As[2][64][72];
  __shared__ alignas(16) _Float16 Bs[2][64][72];

  int tid = threadIdx.x;
  int blk = blockIdx.x;
  int et = blk % 12;
  int nt = blk / 12;
  int n0 = nt * 64, e0 = et * 64;
  int w = tid >> 6, l = tid & 63, lo = l & 15, g = l >> 4;
  int i = tid >> 2, part = tid & 3;

  const _Float16* aop = AO16 + (long)(n0 + i) * E_ + part * 16;
  const float* wop = Wo + (long)(e0 + i) * E_ + part * 16;

  f32x4 acc[4];
#pragma unroll
  for (int ns = 0; ns < 4; ++ns)
#pragma unroll
    for (int q = 0; q < 4; ++q) acc[ns][q] = 0.f;

  auto STAGE = [&](int kb, int bufi) {
    const uint4* ap4 = (const uint4*)(aop + kb);
    uint4 a0 = ap4[0], a1 = ap4[1];
    *(uint4*)&As[bufi][i][part * 16]     = a0;
    *(uint4*)&As[bufi][i][part * 16 + 8] = a1;
    const float4* p = (const float4*)(wop + kb);
    float4 x0 = p[0], x1 = p[1], x2 = p[2], x3 = p[3];
    *(f16x8*)&Bs[bufi][i][part * 16]     = cvt8(x0, x1);
    *(f16x8*)&Bs[bufi][i][part * 16 + 8] = cvt8(x2, x3);
  };

  STAGE(0, 0);
  __syncthreads();
  for (int k = 0; k < 12; ++k) {
    if (k < 11) STAGE((k + 1) * 64, (k + 1) & 1);
    int bi = k & 1;
#pragma unroll
    for (int kc = 0; kc < 2; ++kc) {
      f16x8 af = *(const f16x8*)&As[bi][w * 16 + lo][kc * 32 + g * 8];
#pragma unroll
      for (int ns = 0; ns < 4; ++ns) {
        f16x8 bf = *(const f16x8*)&Bs[bi][ns * 16 + lo][kc * 32 + g * 8];
        acc[ns] = mf16(af, bf, acc[ns]);
      }
    }
    __syncthreads();
  }

  float* Cs = (float*)&As[0][0][0];  // Cs[n][e], stride 69
#pragma unroll
  for (int ns = 0; ns < 4; ++ns)
#pragma unroll
    for (int reg = 0; reg < 4; ++reg)
      Cs[(w * 16 + g * 4 + reg) * 69 + ns * 16 + lo] = acc[ns][reg];
  __syncthreads();

  float tmp[16];
#pragma unroll
  for (int q = 0; q < 16; ++q)
    tmp[q] = Cs[i * 69 + part * 16 + q] + bo[e0 + part * 16 + q];
  float* outp = Out + (long)(n0 + i) * E_ + e0 + part * 16;
#pragma unroll
  for (int q4 = 0; q4 < 4; ++q4)
    ((float4*)outp)[q4] = make_float4(tmp[q4 * 4], tmp[q4 * 4 + 1], tmp[q4 * 4 + 2], tmp[q4 * 4 + 3]);
}

extern "C" void kernel_launch(void* const* d_in, const int* in_sizes, int n_in,
                              void* d_out, int out_size, void* d_ws, size_t ws_size,
                              hipStream_t stream) {
  const float* query = (const float*)d_in[0];
  const float* key   = (const float*)d_in[1];
  const float* value = (const float*)d_in[2];
  const float* rk    = (const float*)d_in[3];
  const float* rw    = (const float*)d_in[4];
  const float* Wq    = (const float*)d_in[5];
  const float* Wk    = (const float*)d_in[6];
  const float* Wv    = (const float*)d_in[7];
  const float* bv    = (const float*)d_in[8];
  const float* Wo    = (const float*)d_in[9];
  const float* bo    = (const float*)d_in[10];
  float* out = (float*)d_out;

  char* wsb = (char*)d_ws;
  _Float16* Qh  = (_Float16*)(wsb);                  // 3,145,728 B
  _Float16* Kh  = (_Float16*)(wsb + 3145728);        // 3,145,728 B
  _Float16* VPT = (_Float16*)(wsb + 6291456);        // 3,244,032 B
  _Float16* VT  = (_Float16*)(wsb + 9535488);        // 3,145,728 B (aliased w/ AO16)
  _Float16* AO16 = VT;  // VT dead after v_proj_mfma; attn writes AO16 after
  __bf16* W1b = (__bf16*)(wsb + 12681216);           // 49,152 B
  __bf16* W2b = (__bf16*)(wsb + 12730368);           // 49,152 B
  float* cb   = (float*)(wsb + 12779520);            // 1,536 B

  prep_rules<<<384, 64, 0, stream>>>(rk, rw, W1b, W2b, cb);
  qk_proj_mfma<<<384, 256, 0, stream>>>(query, key, Wq, Wk, Qh, Kh);
  vT<<<2 * 16 * 12, 256, 0, stream>>>(value, VT);
  v_proj_mfma<<<2 * 17 * 12, 256, 0, stream>>>(Wv, bv, VT, VPT);
  attn_mfma<<<768, 256, 0, stream>>>(Qh, Kh, VPT, W1b, W2b, cb, AO16);
  out_proj_mfma<<<32 * 12, 256, 0, stream>>>(AO16, Wo, bo, out);
}

// Round 9
// 100.689 us; speedup vs baseline: 7.3934x; 1.0052x over previous
//
#include <hip/hip_runtime.h>

#define S_ 1024
#define E_ 768
#define H_ 12
#define R_ 32
#define D_ 64
#define RS_ 1056  // R_+S_

typedef _Float16 f16x8 __attribute__((ext_vector_type(8)));
typedef __bf16   bf16x8 __attribute__((ext_vector_type(8)));
typedef float    f32x4 __attribute__((ext_vector_type(4)));

__device__ __forceinline__ f32x4 mf16(f16x8 a, f16x8 b, f32x4 c) {
  return __builtin_amdgcn_mfma_f32_16x16x32_f16(a, b, c, 0, 0, 0);
}
__device__ __forceinline__ f32x4 mbf(bf16x8 a, bf16x8 b, f32x4 c) {
  return __builtin_amdgcn_mfma_f32_16x16x32_bf16(a, b, c, 0, 0, 0);
}
__device__ __forceinline__ f16x8 cvt8(float4 a, float4 b) {
  f16x8 r;
  r[0] = (_Float16)a.x; r[1] = (_Float16)a.y; r[2] = (_Float16)a.z; r[3] = (_Float16)a.w;
  r[4] = (_Float16)b.x; r[5] = (_Float16)b.y; r[6] = (_Float16)b.z; r[7] = (_Float16)b.w;
  return r;
}

// ---------------------------------------------------------------------------
// Prep: fold fuzzy-rule quadratic form into two GEMM operand matrices.
// ---------------------------------------------------------------------------
__global__ __launch_bounds__(64) void prep_rules(const float* __restrict__ RK,
                                                 const float* __restrict__ RW,
                                                 __bf16* __restrict__ W1b,
                                                 __bf16* __restrict__ W2b,
                                                 float* __restrict__ cb) {
  int hr = blockIdx.x;  // 0..383 = h*32 + r
  int d = threadIdx.x;
  long idx = (long)hr * 64 + d;
  float w = RW[idx];
  float wi = 1.0f / w;
  float w2 = wi * wi;
  float rk = RK[idx];
  W1b[idx] = (__bf16)(-w2 * (1.0f / 524288.0f));
  W2b[idx] = (__bf16)(rk * w2 * (1.0f / 4096.0f));
  float part = rk * rk * w2;
  part += __shfl_xor(part, 1);
  part += __shfl_xor(part, 2);
  part += __shfl_xor(part, 4);
  part += __shfl_xor(part, 8);
  part += __shfl_xor(part, 16);
  part += __shfl_xor(part, 32);
  if (d == 0) cb[hr] = -part * (1.0f / 128.0f);
}

// ---------------------------------------------------------------------------
// Kernel 1: per-head Q/K projections via MFMA, zero LDS.
// ---------------------------------------------------------------------------
__global__ __launch_bounds__(256) void qk_proj_mfma(const float* __restrict__ query,
                                                    const float* __restrict__ key,
                                                    const float* __restrict__ Wq,
                                                    const float* __restrict__ Wk,
                                                    _Float16* __restrict__ Qh,
                                                    _Float16* __restrict__ Kh) {
  int blk = blockIdx.x;
  int st = blk & 15;
  int h  = (blk >> 4) % H_;
  int b  = blk / (16 * H_);
  int tid = threadIdx.x;
  int w = tid >> 6, l = tid & 63, lo = l & 15, g = l >> 4;

  int s_in = st * 64 + w * 16 + lo;
  const float* qp = query + ((long)(b * S_) + s_in) * E_ + h * 64;
  const float* kp = key   + ((long)(b * S_) + s_in) * E_ + h * 64;
  float4 a0 = *(const float4*)(qp + g * 8);
  float4 a1 = *(const float4*)(qp + g * 8 + 4);
  float4 a2 = *(const float4*)(qp + 32 + g * 8);
  float4 a3 = *(const float4*)(qp + 32 + g * 8 + 4);
  f16x8 xq0 = cvt8(a0, a1), xq1 = cvt8(a2, a3);
  a0 = *(const float4*)(kp + g * 8);
  a1 = *(const float4*)(kp + g * 8 + 4);
  a2 = *(const float4*)(kp + 32 + g * 8);
  a3 = *(const float4*)(kp + 32 + g * 8 + 4);
  f16x8 xk0 = cvt8(a0, a1), xk1 = cvt8(a2, a3);

  f32x4 accq[4], acck[4];
#pragma unroll
  for (int ns = 0; ns < 4; ++ns)
#pragma unroll
    for (int q = 0; q < 4; ++q) { accq[ns][q] = 0.f; acck[ns][q] = 0.f; }

#pragma unroll
  for (int ns = 0; ns < 4; ++ns) {
    const float* wqp = Wq + (long)(ns * 16 + lo) * 64;
    const float* wkp = Wk + (long)(ns * 16 + lo) * 64;
    float4 b0 = *(const float4*)(wqp + g * 8);
    float4 b1 = *(const float4*)(wqp + g * 8 + 4);
    float4 b2 = *(const float4*)(wqp + 32 + g * 8);
    float4 b3 = *(const float4*)(wqp + 32 + g * 8 + 4);
    f16x8 bq0 = cvt8(b0, b1), bq1 = cvt8(b2, b3);
    b0 = *(const float4*)(wkp + g * 8);
    b1 = *(const float4*)(wkp + g * 8 + 4);
    b2 = *(const float4*)(wkp + 32 + g * 8);
    b3 = *(const float4*)(wkp + 32 + g * 8 + 4);
    f16x8 bk0 = cvt8(b0, b1), bk1 = cvt8(b2, b3);
    accq[ns] = mf16(xq0, bq0, accq[ns]);
    accq[ns] = mf16(xq1, bq1, accq[ns]);
    acck[ns] = mf16(xk0, bk0, acck[ns]);
    acck[ns] = mf16(xk1, bk1, acck[ns]);
  }

  long rowbase = (long)(b * H_ + h) * S_ + st * 64 + w * 16;
#pragma unroll
  for (int ns = 0; ns < 4; ++ns) {
#pragma unroll
    for (int reg = 0; reg < 4; ++reg) {
      long off = (rowbase + g * 4 + reg) * 64 + ns * 16 + lo;
      Qh[off] = (_Float16)(accq[ns][reg] * 8.0f);
      Kh[off] = (_Float16)acck[ns][reg];
    }
  }
}

// ---------------------------------------------------------------------------
// Kernel 2a: transpose value -> VT16[b][e][s] f16 ([2][768][1024]).
// ---------------------------------------------------------------------------
__global__ __launch_bounds__(256) void vT(const float* __restrict__ value,
                                          _Float16* __restrict__ VT) {
  __shared__ alignas(16) _Float16 Ls[64][72];
  int blk = blockIdx.x;
  int et = blk % 12;
  int st = (blk / 12) % 16;
  int b = blk / (12 * 16);
  int s0 = st * 64, e0 = et * 64;
  int tid = threadIdx.x;
  int j = tid >> 2, part = tid & 3;

  const float4* p = (const float4*)(value + ((long)(b * S_ + s0 + j)) * E_ + e0 + part * 16);
  float4 x0 = p[0], x1 = p[1], x2 = p[2], x3 = p[3];
  *(f16x8*)&Ls[j][part * 16]     = cvt8(x0, x1);
  *(f16x8*)&Ls[j][part * 16 + 8] = cvt8(x2, x3);
  __syncthreads();

  int i = tid >> 2;
  f16x8 o0, o1;
#pragma unroll
  for (int q = 0; q < 8; ++q) o0[q] = Ls[part * 16 + q][i];
#pragma unroll
  for (int q = 0; q < 8; ++q) o1[q] = Ls[part * 16 + 8 + q][i];
  _Float16* op = VT + ((long)(b * E_ + e0 + i)) * S_ + s0 + part * 16;
  *(f16x8*)op = o0;
  *((f16x8*)op + 1) = o1;
}

// ---------------------------------------------------------------------------
// Kernel 2b: MFMA value projection -> VPT[b,h,d,r] f16.
// ---------------------------------------------------------------------------
__global__ __launch_bounds__(256) void v_proj_mfma(const float* __restrict__ Wv,
                                                   const float* __restrict__ bv,
                                                   const _Float16* __restrict__ VT,
                                                   _Float16* __restrict__ VPT) {
  __shared__ alignas(16) _Float16 As[2][64][72];
  __shared__ alignas(16) _Float16 Bs[2][64][72];

  int tid = threadIdx.x;
  int blk = blockIdx.x;
  int et = blk % 12;
  int rt = (blk / 12) % 17;
  int b  = blk / (12 * 17);
  int r0 = rt * 64, e0 = et * 64;
  int w = tid >> 6, l = tid & 63, lo = l & 15, g = l >> 4;
  int i = tid >> 2, part = tid & 3;

  bool rvalid = (r0 + i) < RS_;
  const float* wvp = Wv + (long)(r0 + i) * S_ + part * 16;
  const _Float16* vtp = VT + ((long)(b * E_ + e0 + i)) * S_ + part * 16;

  f32x4 acc[4];
#pragma unroll
  for (int ns = 0; ns < 4; ++ns)
#pragma unroll
    for (int q = 0; q < 4; ++q) acc[ns][q] = 0.f;

  auto STAGE = [&](int kb, int bufi) {
    float4 x0, x1, x2, x3;
    if (rvalid) {
      const float4* p = (const float4*)(wvp + kb);
      x0 = p[0]; x1 = p[1]; x2 = p[2]; x3 = p[3];
    } else {
      x0 = x1 = x2 = x3 = make_float4(0.f, 0.f, 0.f, 0.f);
    }
    *(f16x8*)&As[bufi][i][part * 16]     = cvt8(x0, x1);
    *(f16x8*)&As[bufi][i][part * 16 + 8] = cvt8(x2, x3);
    const uint4* vp4 = (const uint4*)(vtp + kb);
    uint4 b0 = vp4[0], b1 = vp4[1];
    *(uint4*)&Bs[bufi][i][part * 16]     = b0;
    *(uint4*)&Bs[bufi][i][part * 16 + 8] = b1;
  };

  STAGE(0, 0);
  __syncthreads();
  for (int k = 0; k < 16; ++k) {
    if (k < 15) STAGE((k + 1) * 64, (k + 1) & 1);
    int bi = k & 1;
#pragma unroll
    for (int kc = 0; kc < 2; ++kc) {
      f16x8 af = *(const f16x8*)&As[bi][w * 16 + lo][kc * 32 + g * 8];
#pragma unroll
      for (int ns = 0; ns < 4; ++ns) {
        f16x8 bf = *(const f16x8*)&Bs[bi][ns * 16 + lo][kc * 32 + g * 8];
        acc[ns] = mf16(af, bf, acc[ns]);
      }
    }
    __syncthreads();
  }

  float bvr[4];
#pragma unroll
  for (int reg = 0; reg < 4; ++reg) {
    int r = r0 + w * 16 + g * 4 + reg;
    bvr[reg] = (r < RS_) ? bv[r] : 0.f;
  }
  float* Ct = (float*)&As[0][0][0];  // Ct[d][rloc], stride 69
#pragma unroll
  for (int ns = 0; ns < 4; ++ns)
#pragma unroll
    for (int reg = 0; reg < 4; ++reg)
      Ct[(ns * 16 + lo) * 69 + w * 16 + g * 4 + reg] = acc[ns][reg] + bvr[reg];
  __syncthreads();

  if (r0 + part * 16 < RS_) {
    f16x8 o0, o1;
#pragma unroll
    for (int q = 0; q < 8; ++q) o0[q] = (_Float16)Ct[i * 69 + part * 16 + q];
#pragma unroll
    for (int q = 0; q < 8; ++q) o1[q] = (_Float16)Ct[i * 69 + part * 16 + 8 + q];
    _Float16* op = VPT + ((long)((b * H_ + et) * 64 + i)) * RS_ + r0 + part * 16;
    *(f16x8*)op = o0;
    *((f16x8*)op + 1) = o1;
  }
}

// ---------------------------------------------------------------------------
// Kernel 3: MFMA flash attention, swapped QK^T, 4-way key split per q-tile.
// Block = one 16-row q-tile, 4 waves x 256 keys; per-lane online softmax with
// defer-max (THR=8); 4-state merge at end.  grid = B*H*64 = 1536.
// ---------------------------------------------------------------------------
__global__ __launch_bounds__(256) void attn_mfma(
    const _Float16* __restrict__ Qh, const _Float16* __restrict__ Kh,
    const _Float16* __restrict__ VPT, const __bf16* __restrict__ W1b,
    const __bf16* __restrict__ W2b, const float* __restrict__ cb,
    _Float16* __restrict__ AO) {
  __shared__ alignas(16) _Float16 Plds[4][16][40];   // [wave][q=lo][key]
  __shared__ alignas(16) _Float16 fwlds[16][40];     // [q=lo][rule]
  __shared__ float OBl[3][64][17];                   // waves 1..3 O spill
  __shared__ float mrgM[3][16];
  __shared__ float mrgL[3][16];
  __shared__ float Olds[16][68];

  int tid = threadIdx.x;
  int wv = tid >> 6;          // 0..3: key-quarter
  int l = tid & 63;
  int lo = l & 15, g = l >> 4;

  int bh = blockIdx.x >> 6;
  int qt = blockIdx.x & 63;
  int b = bh / H_, h = bh % H_;
  int s0 = qt * 16;

  const _Float16* Qw = Qh + ((long)bh * S_ + s0) * 64;
  const _Float16* Kw = Kh + (long)bh * S_ * 64;
  const _Float16* Vw = VPT + (long)bh * 64 * RS_;

  // Q as B-fragment: row = q = lo, k-slice g*8
  f16x8 qa0 = *(const f16x8*)(Qw + (long)lo * 64 + g * 8);
  f16x8 qa1 = *(const f16x8*)(Qw + (long)lo * 64 + 32 + g * 8);

  // ---- fuzzy branch (wave 0): swapped -> rule = g*4+reg, q = lo
  if (wv == 0) {
    bf16x8 qsq0, qsq1, qbf0, qbf1;
#pragma unroll
    for (int j = 0; j < 8; ++j) {
      float a0 = (float)qa0[j], a1 = (float)qa1[j];
      qbf0[j] = (__bf16)a0;
      qbf1[j] = (__bf16)a1;
      qsq0[j] = (__bf16)(a0 * a0);
      qsq1[j] = (__bf16)(a1 * a1);
    }
    f32x4 z[2];
#pragma unroll
    for (int t = 0; t < 2; ++t) {
#pragma unroll
      for (int j = 0; j < 4; ++j) z[t][j] = cb[h * R_ + t * 16 + g * 4 + j];
      const __bf16* w1p = W1b + ((long)h * R_ + t * 16 + lo) * 64;
      const __bf16* w2p = W2b + ((long)h * R_ + t * 16 + lo) * 64;
      bf16x8 b10 = *(const bf16x8*)(w1p + g * 8);
      bf16x8 b11 = *(const bf16x8*)(w1p + 32 + g * 8);
      bf16x8 b20 = *(const bf16x8*)(w2p + g * 8);
      bf16x8 b21 = *(const bf16x8*)(w2p + 32 + g * 8);
      z[t] = mbf(b10, qsq0, z[t]);   // A = rules, B = q
      z[t] = mbf(b11, qsq1, z[t]);
      z[t] = mbf(b20, qbf0, z[t]);
      z[t] = mbf(b21, qbf1, z[t]);
    }
    float zm = z[0][0];
#pragma unroll
    for (int j = 1; j < 4; ++j) zm = fmaxf(zm, z[0][j]);
#pragma unroll
    for (int j = 0; j < 4; ++j) zm = fmaxf(zm, z[1][j]);
    zm = fmaxf(zm, __shfl_xor(zm, 16));
    zm = fmaxf(zm, __shfl_xor(zm, 32));
    float ez[2][4], zsum = 0.f;
#pragma unroll
    for (int t = 0; t < 2; ++t)
#pragma unroll
      for (int j = 0; j < 4; ++j) { ez[t][j] = __expf(z[t][j] - zm); zsum += ez[t][j]; }
    zsum += __shfl_xor(zsum, 16);
    zsum += __shfl_xor(zsum, 32);
    float zin = 1.0f / zsum;
#pragma unroll
    for (int t = 0; t < 2; ++t)
#pragma unroll
      for (int j = 0; j < 4; ++j)
        fwlds[lo][t * 16 + g * 4 + j] = (_Float16)(ez[t][j] * zin);
  }

  // ---- flash key loop: 8 chunks of 32 keys (wave wv owns quarter wv)
  f32x4 O[4];
#pragma unroll
  for (int dt = 0; dt < 4; ++dt)
#pragma unroll
    for (int j = 0; j < 4; ++j) O[dt][j] = 0.f;
  float m = -__builtin_inff();
  float ellp = 0.f;

  int kb0 = wv * 256;
  const _Float16* kp0 = Kw + (long)(kb0 + lo) * 64 + g * 8;
  const _Float16* kp1 = Kw + (long)(kb0 + 16 + lo) * 64 + g * 8;
  f16x8 kf00 = *(const f16x8*)(kp0);
  f16x8 kf01 = *(const f16x8*)(kp0 + 32);
  f16x8 kf10 = *(const f16x8*)(kp1);
  f16x8 kf11 = *(const f16x8*)(kp1 + 32);

  for (int c = 0; c < 8; ++c) {
    int kb = kb0 + c * 32;
    f16x8 nf00, nf01, nf10, nf11;
    if (c < 7) {  // prefetch next chunk's K fragments
      const _Float16* np0 = Kw + (long)(kb + 32 + lo) * 64 + g * 8;
      const _Float16* np1 = Kw + (long)(kb + 48 + lo) * 64 + g * 8;
      nf00 = *(const f16x8*)(np0);
      nf01 = *(const f16x8*)(np0 + 32);
      nf10 = *(const f16x8*)(np1);
      nf11 = *(const f16x8*)(np1 + 32);
    }
    f32x4 e0, e1;
#pragma unroll
    for (int j = 0; j < 4; ++j) { e0[j] = 0.f; e1[j] = 0.f; }
    e0 = mf16(kf00, qa0, e0);  // A = K rows, B = Q -> e0[j]: key kb+g*4+j, q=lo
    e0 = mf16(kf01, qa1, e0);
    e1 = mf16(kf10, qa0, e1);  // keys kb+16+g*4+j
    e1 = mf16(kf11, qa1, e1);

    float pmax = e0[0];
#pragma unroll
    for (int j = 1; j < 4; ++j) pmax = fmaxf(pmax, e0[j]);
#pragma unroll
    for (int j = 0; j < 4; ++j) pmax = fmaxf(pmax, e1[j]);
    pmax = fmaxf(pmax, __shfl_xor(pmax, 16));
    pmax = fmaxf(pmax, __shfl_xor(pmax, 32));
    if (__any(pmax > m + 8.0f)) {  // defer-max
      float mn = fmaxf(m, pmax);
      float sc = __expf(m - mn);
      m = mn;
      ellp *= sc;
#pragma unroll
      for (int dt = 0; dt < 4; ++dt)
#pragma unroll
        for (int j = 0; j < 4; ++j) O[dt][j] *= sc;
    }
    float p0[4], p1[4], s8 = 0.f;
#pragma unroll
    for (int j = 0; j < 4; ++j) {
      p0[j] = __expf(e0[j] - m);
      p1[j] = __expf(e1[j] - m);
      s8 += p0[j] + p1[j];
    }
    ellp += s8;
#pragma unroll
    for (int j = 0; j < 4; ++j) {
      Plds[wv][lo][g * 4 + j] = (_Float16)p0[j];
      Plds[wv][lo][16 + g * 4 + j] = (_Float16)p1[j];
    }
    f16x8 pb = *(const f16x8*)&Plds[wv][lo][g * 8];  // B-frag: row q=lo, k=keys
#pragma unroll
    for (int dt = 0; dt < 4; ++dt) {
      f16x8 va = *(const f16x8*)(Vw + (long)(dt * 16 + lo) * RS_ + R_ + kb + g * 8);
      O[dt] = mf16(va, pb, O[dt]);
    }
    kf00 = nf00; kf01 = nf01; kf10 = nf10; kf11 = nf11;
  }

  // per-wave ell: cross-g reduce
  float ell = ellp;
  ell += __shfl_xor(ell, 16);
  ell += __shfl_xor(ell, 32);

  // ---- merge the four waves' states (all per-lane, q = lo)
  if (wv > 0) {
#pragma unroll
    for (int dt = 0; dt < 4; ++dt)
#pragma unroll
      for (int j = 0; j < 4; ++j) OBl[wv - 1][dt * 16 + g * 4 + j][lo] = O[dt][j];
    if (l < 16) {
      mrgM[wv - 1][l] = m;
      mrgL[wv - 1][l] = ell;
    }
  }
  __syncthreads();
  if (wv == 0) {
    float m1 = mrgM[0][lo], m2 = mrgM[1][lo], m3 = mrgM[2][lo];
    float l1 = mrgL[0][lo], l2 = mrgL[1][lo], l3 = mrgL[2][lo];
    float mM = fmaxf(fmaxf(m, m1), fmaxf(m2, m3));
    float s0v = __expf(m - mM);
    float s1v = __expf(m1 - mM);
    float s2v = __expf(m2 - mM);
    float s3v = __expf(m3 - mM);
    float iv = 1.0f / (ell * s0v + l1 * s1v + l2 * s2v + l3 * s3v);
    float f0 = s0v * iv, f1 = s1v * iv, f2 = s2v * iv, f3 = s3v * iv;
#pragma unroll
    for (int dt = 0; dt < 4; ++dt)
#pragma unroll
      for (int j = 0; j < 4; ++j) {
        int row = dt * 16 + g * 4 + j;
        O[dt][j] = O[dt][j] * f0 + OBl[0][row][lo] * f1 +
                   OBl[1][row][lo] * f2 + OBl[2][row][lo] * f3;
      }
    // rules contribution (already normalized)
    f16x8 fb = *(const f16x8*)&fwlds[lo][g * 8];
#pragma unroll
    for (int dt = 0; dt < 4; ++dt) {
      f16x8 va = *(const f16x8*)(Vw + (long)(dt * 16 + lo) * RS_ + g * 8);
      O[dt] = mf16(va, fb, O[dt]);
    }
#pragma unroll
    for (int dt = 0; dt < 4; ++dt)
#pragma unroll
      for (int j = 0; j < 4; ++j) Olds[lo][dt * 16 + g * 4 + j] = O[dt][j];
  }
  __syncthreads();
  for (int idx = tid; idx < 16 * 64; idx += 256) {
    int row = idx >> 6;
    int col = idx & 63;
    AO[((long)(b * S_ + s0 + row)) * E_ + h * 64 + col] = (_Float16)Olds[row][col];
  }
}

// ---------------------------------------------------------------------------
// Kernel 4: MFMA output projection. C[n,e] = sum_f AO16[n,f]*Wo[e,f] + bo[e].
// ---------------------------------------------------------------------------
__global__ __launch_bounds__(256) void out_proj_mfma(const _Float16* __restrict__ AO16,
                                                     const float* __restrict__ Wo,
                                                     const float* __restrict__ bo,
                                                     float* __restrict__ Out) {
  __shared__ alignas(16) _Float16 As[2][64][72];
  __shared__ alignas(16) _Float16 Bs[2][64][72];

  int tid = threadIdx.x;
  int blk = blockIdx.x;
  int et = blk % 12;
  int nt = blk / 12;
  int n0 = nt * 64, e0 = et * 64;
  int w = tid >> 6, l = tid & 63, lo = l & 15, g = l >> 4;
  int i = tid >> 2, part = tid & 3;

  const _Float16* aop = AO16 + (long)(n0 + i) * E_ + part * 16;
  const float* wop = Wo + (long)(e0 + i) * E_ + part * 16;

  f32x4 acc[4];
#pragma unroll
  for (int ns = 0; ns < 4; ++ns)
#pragma unroll
    for (int q = 0; q < 4; ++q) acc[ns][q] = 0.f;

  auto STAGE = [&](int kb, int bufi) {
    const uint4* ap4 = (const uint4*)(aop + kb);
    uint4 a0 = ap4[0], a1 = ap4[1];
    *(uint4*)&As[bufi][i][part * 16]     = a0;
    *(uint4*)&As[bufi][i][part * 16 + 8] = a1;
    const float4* p = (const float4*)(wop + kb);
    float4 x0 = p[0], x1 = p[1], x2 = p[2], x3 = p[3];
    *(f16x8*)&Bs[bufi][i][part * 16]     = cvt8(x0, x1);
    *(f16x8*)&Bs[bufi][i][part * 16 + 8] = cvt8(x2, x3);
  };

  STAGE(0, 0);
  __syncthreads();
  for (int k = 0; k < 12; ++k) {
    if (k < 11) STAGE((k + 1) * 64, (k + 1) & 1);
    int bi = k & 1;
#pragma unroll
    for (int kc = 0; kc < 2; ++kc) {
      f16x8 af = *(const f16x8*)&As[bi][w * 16 + lo][kc * 32 + g * 8];
#pragma unroll
      for (int ns = 0; ns < 4; ++ns) {
        f16x8 bf = *(const f16x8*)&Bs[bi][ns * 16 + lo][kc * 32 + g * 8];
        acc[ns] = mf16(af, bf, acc[ns]);
      }
    }
    __syncthreads();
  }

  float* Cs = (float*)&As[0][0][0];  // Cs[n][e], stride 69
#pragma unroll
  for (int ns = 0; ns < 4; ++ns)
#pragma unroll
    for (int reg = 0; reg < 4; ++reg)
      Cs[(w * 16 + g * 4 + reg) * 69 + ns * 16 + lo] = acc[ns][reg];
  __syncthreads();

  float tmp[16];
#pragma unroll
  for (int q = 0; q < 16; ++q)
    tmp[q] = Cs[i * 69 + part * 16 + q] + bo[e0 + part * 16 + q];
  float* outp = Out + (long)(n0 + i) * E_ + e0 + part * 16;
#pragma unroll
  for (int q4 = 0; q4 < 4; ++q4)
    ((float4*)outp)[q4] = make_float4(tmp[q4 * 4], tmp[q4 * 4 + 1], tmp[q4 * 4 + 2], tmp[q4 * 4 + 3]);
}

extern "C" void kernel_launch(void* const* d_in, const int* in_sizes, int n_in,
                              void* d_out, int out_size, void* d_ws, size_t ws_size,
                              hipStream_t stream) {
  const float* query = (const float*)d_in[0];
  const float* key   = (const float*)d_in[1];
  const float* value = (const float*)d_in[2];
  const float* rk    = (const float*)d_in[3];
  const float* rw    = (const float*)d_in[4];
  const float* Wq    = (const float*)d_in[5];
  const float* Wk    = (const float*)d_in[6];
  const float* Wv    = (const float*)d_in[7];
  const float* bv    = (const float*)d_in[8];
  const float* Wo    = (const float*)d_in[9];
  const float* bo    = (const float*)d_in[10];
  float* out = (float*)d_out;

  char* wsb = (char*)d_ws;
  _Float16* Qh  = (_Float16*)(wsb);                  // 3,145,728 B
  _Float16* Kh  = (_Float16*)(wsb + 3145728);        // 3,145,728 B
  _Float16* VPT = (_Float16*)(wsb + 6291456);        // 3,244,032 B
  _Float16* VT  = (_Float16*)(wsb + 9535488);        // 3,145,728 B (aliased w/ AO16)
  _Float16* AO16 = VT;  // VT dead after v_proj_mfma; attn writes AO16 after
  __bf16* W1b = (__bf16*)(wsb + 12681216);           // 49,152 B
  __bf16* W2b = (__bf16*)(wsb + 12730368);           // 49,152 B
  float* cb   = (float*)(wsb + 12779520);            // 1,536 B

  prep_rules<<<384, 64, 0, stream>>>(rk, rw, W1b, W2b, cb);
  qk_proj_mfma<<<384, 256, 0, stream>>>(query, key, Wq, Wk, Qh, Kh);
  vT<<<2 * 16 * 12, 256, 0, stream>>>(value, VT);
  v_proj_mfma<<<2 * 17 * 12, 256, 0, stream>>>(Wv, bv, VT, VPT);
  attn_mfma<<<1536, 256, 0, stream>>>(Qh, Kh, VPT, W1b, W2b, cb, AO16);
  out_proj_mfma<<<32 * 12, 256, 0, stream>>>(AO16, Wo, bo, out);
}

// Round 10
// 100.558 us; speedup vs baseline: 7.4031x; 1.0013x over previous
//
#include <hip/hip_runtime.h>

#define S_ 1024
#define E_ 768
#define H_ 12
#define R_ 32
#define D_ 64
#define RS_ 1056  // R_+S_

// exp2-domain constants: L = log2(e), LN2 = 1/L
#define L2E 1.4426950408889634f
#define LN2F 0.6931471805599453f

#if __has_builtin(__builtin_amdgcn_exp2f)
#define EXP2(x) __builtin_amdgcn_exp2f(x)
#else
#define EXP2(x) exp2f(x)
#endif

typedef _Float16 f16x8 __attribute__((ext_vector_type(8)));
typedef __bf16   bf16x8 __attribute__((ext_vector_type(8)));
typedef float    f32x4 __attribute__((ext_vector_type(4)));

__device__ __forceinline__ f32x4 mf16(f16x8 a, f16x8 b, f32x4 c) {
  return __builtin_amdgcn_mfma_f32_16x16x32_f16(a, b, c, 0, 0, 0);
}
__device__ __forceinline__ f32x4 mbf(bf16x8 a, bf16x8 b, f32x4 c) {
  return __builtin_amdgcn_mfma_f32_16x16x32_bf16(a, b, c, 0, 0, 0);
}
__device__ __forceinline__ f16x8 cvt8(float4 a, float4 b) {
  f16x8 r;
  r[0] = (_Float16)a.x; r[1] = (_Float16)a.y; r[2] = (_Float16)a.z; r[3] = (_Float16)a.w;
  r[4] = (_Float16)b.x; r[5] = (_Float16)b.y; r[6] = (_Float16)b.z; r[7] = (_Float16)b.w;
  return r;
}

// ---------------------------------------------------------------------------
// Prep: fold fuzzy quadratic form into GEMM operands, exp2 domain.
// z2 = L*z_nat = sum_d Qh^2*W1' + Qh*W2' + c', with Qh = 8*L*q:
// W1' = -w^-2*LN2/524288, W2' = rk*w^-2/4096, c' = -L*sum(rk^2 w^-2)/128.
// ---------------------------------------------------------------------------
__global__ __launch_bounds__(64) void prep_rules(const float* __restrict__ RK,
                                                 const float* __restrict__ RW,
                                                 __bf16* __restrict__ W1b,
                                                 __bf16* __restrict__ W2b,
                                                 float* __restrict__ cb) {
  int hr = blockIdx.x;  // 0..383 = h*32 + r
  int d = threadIdx.x;
  long idx = (long)hr * 64 + d;
  float w = RW[idx];
  float wi = 1.0f / w;
  float w2 = wi * wi;
  float rk = RK[idx];
  W1b[idx] = (__bf16)(-w2 * (LN2F / 524288.0f));
  W2b[idx] = (__bf16)(rk * w2 * (1.0f / 4096.0f));
  float part = rk * rk * w2;
  part += __shfl_xor(part, 1);
  part += __shfl_xor(part, 2);
  part += __shfl_xor(part, 4);
  part += __shfl_xor(part, 8);
  part += __shfl_xor(part, 16);
  part += __shfl_xor(part, 32);
  if (d == 0) cb[hr] = -part * (L2E / 128.0f);
}

// ---------------------------------------------------------------------------
// Kernel 1: per-head Q/K projections via MFMA, zero LDS. Q scaled 8*log2(e).
// ---------------------------------------------------------------------------
__global__ __launch_bounds__(256) void qk_proj_mfma(const float* __restrict__ query,
                                                    const float* __restrict__ key,
                                                    const float* __restrict__ Wq,
                                                    const float* __restrict__ Wk,
                                                    _Float16* __restrict__ Qh,
                                                    _Float16* __restrict__ Kh) {
  int blk = blockIdx.x;
  int st = blk & 15;
  int h  = (blk >> 4) % H_;
  int b  = blk / (16 * H_);
  int tid = threadIdx.x;
  int w = tid >> 6, l = tid & 63, lo = l & 15, g = l >> 4;

  int s_in = st * 64 + w * 16 + lo;
  const float* qp = query + ((long)(b * S_) + s_in) * E_ + h * 64;
  const float* kp = key   + ((long)(b * S_) + s_in) * E_ + h * 64;
  float4 a0 = *(const float4*)(qp + g * 8);
  float4 a1 = *(const float4*)(qp + g * 8 + 4);
  float4 a2 = *(const float4*)(qp + 32 + g * 8);
  float4 a3 = *(const float4*)(qp + 32 + g * 8 + 4);
  f16x8 xq0 = cvt8(a0, a1), xq1 = cvt8(a2, a3);
  a0 = *(const float4*)(kp + g * 8);
  a1 = *(const float4*)(kp + g * 8 + 4);
  a2 = *(const float4*)(kp + 32 + g * 8);
  a3 = *(const float4*)(kp + 32 + g * 8 + 4);
  f16x8 xk0 = cvt8(a0, a1), xk1 = cvt8(a2, a3);

  f32x4 accq[4], acck[4];
#pragma unroll
  for (int ns = 0; ns < 4; ++ns)
#pragma unroll
    for (int q = 0; q < 4; ++q) { accq[ns][q] = 0.f; acck[ns][q] = 0.f; }

#pragma unroll
  for (int ns = 0; ns < 4; ++ns) {
    const float* wqp = Wq + (long)(ns * 16 + lo) * 64;
    const float* wkp = Wk + (long)(ns * 16 + lo) * 64;
    float4 b0 = *(const float4*)(wqp + g * 8);
    float4 b1 = *(const float4*)(wqp + g * 8 + 4);
    float4 b2 = *(const float4*)(wqp + 32 + g * 8);
    float4 b3 = *(const float4*)(wqp + 32 + g * 8 + 4);
    f16x8 bq0 = cvt8(b0, b1), bq1 = cvt8(b2, b3);
    b0 = *(const float4*)(wkp + g * 8);
    b1 = *(const float4*)(wkp + g * 8 + 4);
    b2 = *(const float4*)(wkp + 32 + g * 8);
    b3 = *(const float4*)(wkp + 32 + g * 8 + 4);
    f16x8 bk0 = cvt8(b0, b1), bk1 = cvt8(b2, b3);
    accq[ns] = mf16(xq0, bq0, accq[ns]);
    accq[ns] = mf16(xq1, bq1, accq[ns]);
    acck[ns] = mf16(xk0, bk0, acck[ns]);
    acck[ns] = mf16(xk1, bk1, acck[ns]);
  }

  long rowbase = (long)(b * H_ + h) * S_ + st * 64 + w * 16;
#pragma unroll
  for (int ns = 0; ns < 4; ++ns) {
#pragma unroll
    for (int reg = 0; reg < 4; ++reg) {
      long off = (rowbase + g * 4 + reg) * 64 + ns * 16 + lo;
      Qh[off] = (_Float16)(accq[ns][reg] * (8.0f * L2E));
      Kh[off] = (_Float16)acck[ns][reg];
    }
  }
}

// ---------------------------------------------------------------------------
// Kernel 2: MFMA value projection, value staged DIRECTLY (fused transpose).
// Per b: C[r,e] = sum_s Wv[r,s]*value[b,s,e] -> VPT[b,h,d,r] = C + bv[r].
// ---------------------------------------------------------------------------
__global__ __launch_bounds__(256) void v_proj_mfma(const float* __restrict__ Wv,
                                                   const float* __restrict__ bv,
                                                   const float* __restrict__ value,
                                                   _Float16* __restrict__ VPT) {
  __shared__ alignas(16) _Float16 As[2][64][72];
  __shared__ alignas(16) _Float16 Bs[2][64][72];

  int tid = threadIdx.x;
  int blk = blockIdx.x;
  int et = blk % 12;
  int rt = (blk / 12) % 17;
  int b  = blk / (12 * 17);
  int r0 = rt * 64, e0 = et * 64;
  int w = tid >> 6, l = tid & 63, lo = l & 15, g = l >> 4;
  int i = tid >> 2, part = tid & 3;

  bool rvalid = (r0 + i) < RS_;
  const float* wvp = Wv + (long)(r0 + i) * S_ + part * 16;
  const float* vbase = value + (long)(b * S_) * E_ + e0 + part * 16;

  f32x4 acc[4];
#pragma unroll
  for (int ns = 0; ns < 4; ++ns)
#pragma unroll
    for (int q = 0; q < 4; ++q) acc[ns][q] = 0.f;

  auto STAGE = [&](int kb, int bufi) {
    // A: Wv rows (K-contiguous)
    float4 x0, x1, x2, x3;
    if (rvalid) {
      const float4* p = (const float4*)(wvp + kb);
      x0 = p[0]; x1 = p[1]; x2 = p[2]; x3 = p[3];
    } else {
      x0 = x1 = x2 = x3 = make_float4(0.f, 0.f, 0.f, 0.f);
    }
    *(f16x8*)&As[bufi][i][part * 16]     = cvt8(x0, x1);
    *(f16x8*)&As[bufi][i][part * 16 + 8] = cvt8(x2, x3);
    // B: value[kb+i][e0+part*16..+15] -> transposed Bs[e_local][k_local=i]
    const float4* vp = (const float4*)(vbase + (long)(kb + i) * E_);
    float4 y0 = vp[0], y1 = vp[1], y2 = vp[2], y3 = vp[3];
    Bs[bufi][part * 16 +  0][i] = (_Float16)y0.x;
    Bs[bufi][part * 16 +  1][i] = (_Float16)y0.y;
    Bs[bufi][part * 16 +  2][i] = (_Float16)y0.z;
    Bs[bufi][part * 16 +  3][i] = (_Float16)y0.w;
    Bs[bufi][part * 16 +  4][i] = (_Float16)y1.x;
    Bs[bufi][part * 16 +  5][i] = (_Float16)y1.y;
    Bs[bufi][part * 16 +  6][i] = (_Float16)y1.z;
    Bs[bufi][part * 16 +  7][i] = (_Float16)y1.w;
    Bs[bufi][part * 16 +  8][i] = (_Float16)y2.x;
    Bs[bufi][part * 16 +  9][i] = (_Float16)y2.y;
    Bs[bufi][part * 16 + 10][i] = (_Float16)y2.z;
    Bs[bufi][part * 16 + 11][i] = (_Float16)y2.w;
    Bs[bufi][part * 16 + 12][i] = (_Float16)y3.x;
    Bs[bufi][part * 16 + 13][i] = (_Float16)y3.y;
    Bs[bufi][part * 16 + 14][i] = (_Float16)y3.z;
    Bs[bufi][part * 16 + 15][i] = (_Float16)y3.w;
  };

  STAGE(0, 0);
  __syncthreads();
  for (int k = 0; k < 16; ++k) {
    if (k < 15) STAGE((k + 1) * 64, (k + 1) & 1);
    int bi = k & 1;
#pragma unroll
    for (int kc = 0; kc < 2; ++kc) {
      f16x8 af = *(const f16x8*)&As[bi][w * 16 + lo][kc * 32 + g * 8];
#pragma unroll
      for (int ns = 0; ns < 4; ++ns) {
        f16x8 bf = *(const f16x8*)&Bs[bi][ns * 16 + lo][kc * 32 + g * 8];
        acc[ns] = mf16(af, bf, acc[ns]);
      }
    }
    __syncthreads();
  }

  float bvr[4];
#pragma unroll
  for (int reg = 0; reg < 4; ++reg) {
    int r = r0 + w * 16 + g * 4 + reg;
    bvr[reg] = (r < RS_) ? bv[r] : 0.f;
  }
  float* Ct = (float*)&As[0][0][0];  // Ct[d][rloc], stride 69
#pragma unroll
  for (int ns = 0; ns < 4; ++ns)
#pragma unroll
    for (int reg = 0; reg < 4; ++reg)
      Ct[(ns * 16 + lo) * 69 + w * 16 + g * 4 + reg] = acc[ns][reg] + bvr[reg];
  __syncthreads();

  if (r0 + part * 16 < RS_) {
    f16x8 o0, o1;
#pragma unroll
    for (int q = 0; q < 8; ++q) o0[q] = (_Float16)Ct[i * 69 + part * 16 + q];
#pragma unroll
    for (int q = 0; q < 8; ++q) o1[q] = (_Float16)Ct[i * 69 + part * 16 + 8 + q];
    _Float16* op = VPT + ((long)((b * H_ + et) * 64 + i)) * RS_ + r0 + part * 16;
    *(f16x8*)op = o0;
    *((f16x8*)op + 1) = o1;
  }
}

// ---------------------------------------------------------------------------
// Kernel 3: MFMA flash attention, swapped QK^T, exp2 domain, speculative exp.
// Block = one 16-row q-tile, 4 waves x 256 keys; per-lane online softmax.
// ---------------------------------------------------------------------------
__global__ __launch_bounds__(256) void attn_mfma(
    const _Float16* __restrict__ Qh, const _Float16* __restrict__ Kh,
    const _Float16* __restrict__ VPT, const __bf16* __restrict__ W1b,
    const __bf16* __restrict__ W2b, const float* __restrict__ cb,
    _Float16* __restrict__ AO) {
  __shared__ alignas(16) _Float16 Plds[4][16][40];   // [wave][q=lo][key]
  __shared__ alignas(16) _Float16 fwlds[16][40];     // [q=lo][rule]
  __shared__ float OBl[3][64][17];                   // waves 1..3 O spill
  __shared__ float mrgM[3][16];
  __shared__ float mrgL[3][16];
  __shared__ float Olds[16][68];

  int tid = threadIdx.x;
  int wv = tid >> 6;          // 0..3: key-quarter
  int l = tid & 63;
  int lo = l & 15, g = l >> 4;

  int bh = blockIdx.x >> 6;
  int qt = blockIdx.x & 63;
  int b = bh / H_, h = bh % H_;
  int s0 = qt * 16;

  const _Float16* Qw = Qh + ((long)bh * S_ + s0) * 64;
  const _Float16* Kw = Kh + (long)bh * S_ * 64;
  const _Float16* Vw = VPT + (long)bh * 64 * RS_;

  f16x8 qa0 = *(const f16x8*)(Qw + (long)lo * 64 + g * 8);
  f16x8 qa1 = *(const f16x8*)(Qw + (long)lo * 64 + 32 + g * 8);

  // ---- fuzzy branch (wave 0): swapped -> rule = g*4+reg, q = lo (exp2 dom)
  if (wv == 0) {
    bf16x8 qsq0, qsq1, qbf0, qbf1;
#pragma unroll
    for (int j = 0; j < 8; ++j) {
      float a0 = (float)qa0[j], a1 = (float)qa1[j];
      qbf0[j] = (__bf16)a0;
      qbf1[j] = (__bf16)a1;
      qsq0[j] = (__bf16)(a0 * a0);
      qsq1[j] = (__bf16)(a1 * a1);
    }
    f32x4 z[2];
#pragma unroll
    for (int t = 0; t < 2; ++t) {
#pragma unroll
      for (int j = 0; j < 4; ++j) z[t][j] = cb[h * R_ + t * 16 + g * 4 + j];
      const __bf16* w1p = W1b + ((long)h * R_ + t * 16 + lo) * 64;
      const __bf16* w2p = W2b + ((long)h * R_ + t * 16 + lo) * 64;
      bf16x8 b10 = *(const bf16x8*)(w1p + g * 8);
      bf16x8 b11 = *(const bf16x8*)(w1p + 32 + g * 8);
      bf16x8 b20 = *(const bf16x8*)(w2p + g * 8);
      bf16x8 b21 = *(const bf16x8*)(w2p + 32 + g * 8);
      z[t] = mbf(b10, qsq0, z[t]);   // A = rules, B = q
      z[t] = mbf(b11, qsq1, z[t]);
      z[t] = mbf(b20, qbf0, z[t]);
      z[t] = mbf(b21, qbf1, z[t]);
    }
    float zm = z[0][0];
#pragma unroll
    for (int j = 1; j < 4; ++j) zm = fmaxf(zm, z[0][j]);
#pragma unroll
    for (int j = 0; j < 4; ++j) zm = fmaxf(zm, z[1][j]);
    zm = fmaxf(zm, __shfl_xor(zm, 16));
    zm = fmaxf(zm, __shfl_xor(zm, 32));
    float ez[2][4], zsum = 0.f;
#pragma unroll
    for (int t = 0; t < 2; ++t)
#pragma unroll
      for (int j = 0; j < 4; ++j) { ez[t][j] = EXP2(z[t][j] - zm); zsum += ez[t][j]; }
    zsum += __shfl_xor(zsum, 16);
    zsum += __shfl_xor(zsum, 32);
    float zin = 1.0f / zsum;
#pragma unroll
    for (int t = 0; t < 2; ++t)
#pragma unroll
      for (int j = 0; j < 4; ++j)
        fwlds[lo][t * 16 + g * 4 + j] = (_Float16)(ez[t][j] * zin);
  }

  // ---- flash key loop: 8 chunks of 32 keys (wave wv owns quarter wv)
  f32x4 O[4];
#pragma unroll
  for (int dt = 0; dt < 4; ++dt)
#pragma unroll
    for (int j = 0; j < 4; ++j) O[dt][j] = 0.f;
  float m = -__builtin_inff();
  float ellp = 0.f;

  int kb0 = wv * 256;
  const _Float16* kp0 = Kw + (long)(kb0 + lo) * 64 + g * 8;
  const _Float16* kp1 = Kw + (long)(kb0 + 16 + lo) * 64 + g * 8;
  f16x8 kf00 = *(const f16x8*)(kp0);
  f16x8 kf01 = *(const f16x8*)(kp0 + 32);
  f16x8 kf10 = *(const f16x8*)(kp1);
  f16x8 kf11 = *(const f16x8*)(kp1 + 32);

  for (int c = 0; c < 8; ++c) {
    int kb = kb0 + c * 32;
    f16x8 nf00, nf01, nf10, nf11;
    if (c < 7) {  // prefetch next chunk's K fragments
      const _Float16* np0 = Kw + (long)(kb + 32 + lo) * 64 + g * 8;
      const _Float16* np1 = Kw + (long)(kb + 48 + lo) * 64 + g * 8;
      nf00 = *(const f16x8*)(np0);
      nf01 = *(const f16x8*)(np0 + 32);
      nf10 = *(const f16x8*)(np1);
      nf11 = *(const f16x8*)(np1 + 32);
    }
    f32x4 e0, e1;
#pragma unroll
    for (int j = 0; j < 4; ++j) { e0[j] = 0.f; e1[j] = 0.f; }
    e0 = mf16(kf00, qa0, e0);  // e0[j]: key kb+g*4+j, q=lo  (exp2 domain)
    e0 = mf16(kf01, qa1, e0);
    e1 = mf16(kf10, qa0, e1);  // keys kb+16+g*4+j
    e1 = mf16(kf11, qa1, e1);

    // issue V loads early (no dependence on e)
    f16x8 va0 = *(const f16x8*)(Vw + (long)(0 * 16 + lo) * RS_ + R_ + kb + g * 8);
    f16x8 va1 = *(const f16x8*)(Vw + (long)(1 * 16 + lo) * RS_ + R_ + kb + g * 8);
    f16x8 va2 = *(const f16x8*)(Vw + (long)(2 * 16 + lo) * RS_ + R_ + kb + g * 8);
    f16x8 va3 = *(const f16x8*)(Vw + (long)(3 * 16 + lo) * RS_ + R_ + kb + g * 8);

    // speculative exps with stale m (overlaps the pmax reduce)
    float p0[4], p1[4];
#pragma unroll
    for (int j = 0; j < 4; ++j) {
      p0[j] = EXP2(e0[j] - m);
      p1[j] = EXP2(e1[j] - m);
    }
    float pmax = e0[0];
#pragma unroll
    for (int j = 1; j < 4; ++j) pmax = fmaxf(pmax, e0[j]);
#pragma unroll
    for (int j = 0; j < 4; ++j) pmax = fmaxf(pmax, e1[j]);
    pmax = fmaxf(pmax, __shfl_xor(pmax, 16));
    pmax = fmaxf(pmax, __shfl_xor(pmax, 32));
    if (__any(pmax > m + 11.5f)) {  // rescale needed (rare): redo
      float mn = fmaxf(m, pmax);
      float sc = EXP2(m - mn);
      ellp *= sc;
#pragma unroll
      for (int dt = 0; dt < 4; ++dt)
#pragma unroll
        for (int j = 0; j < 4; ++j) O[dt][j] *= sc;
#pragma unroll
      for (int j = 0; j < 4; ++j) {
        p0[j] = EXP2(e0[j] - mn);
        p1[j] = EXP2(e1[j] - mn);
      }
      m = mn;
    }
    float s8 = 0.f;
#pragma unroll
    for (int j = 0; j < 4; ++j) s8 += p0[j] + p1[j];
    ellp += s8;
#pragma unroll
    for (int j = 0; j < 4; ++j) {
      Plds[wv][lo][g * 4 + j] = (_Float16)p0[j];
      Plds[wv][lo][16 + g * 4 + j] = (_Float16)p1[j];
    }
    f16x8 pb = *(const f16x8*)&Plds[wv][lo][g * 8];  // B-frag: row q=lo
    O[0] = mf16(va0, pb, O[0]);
    O[1] = mf16(va1, pb, O[1]);
    O[2] = mf16(va2, pb, O[2]);
    O[3] = mf16(va3, pb, O[3]);
    kf00 = nf00; kf01 = nf01; kf10 = nf10; kf11 = nf11;
  }

  // per-wave ell: cross-g reduce
  float ell = ellp;
  ell += __shfl_xor(ell, 16);
  ell += __shfl_xor(ell, 32);

  // ---- merge the four waves' states (all per-lane, q = lo)
  if (wv > 0) {
#pragma unroll
    for (int dt = 0; dt < 4; ++dt)
#pragma unroll
      for (int j = 0; j < 4; ++j) OBl[wv - 1][dt * 16 + g * 4 + j][lo] = O[dt][j];
    if (l < 16) {
      mrgM[wv - 1][l] = m;
      mrgL[wv - 1][l] = ell;
    }
  }
  __syncthreads();
  if (wv == 0) {
    float m1 = mrgM[0][lo], m2 = mrgM[1][lo], m3 = mrgM[2][lo];
    float l1 = mrgL[0][lo], l2 = mrgL[1][lo], l3 = mrgL[2][lo];
    float mM = fmaxf(fmaxf(m, m1), fmaxf(m2, m3));
    float s0v = EXP2(m - mM);
    float s1v = EXP2(m1 - mM);
    float s2v = EXP2(m2 - mM);
    float s3v = EXP2(m3 - mM);
    float iv = 1.0f / (ell * s0v + l1 * s1v + l2 * s2v + l3 * s3v);
    float f0 = s0v * iv, f1 = s1v * iv, f2 = s2v * iv, f3 = s3v * iv;
#pragma unroll
    for (int dt = 0; dt < 4; ++dt)
#pragma unroll
      for (int j = 0; j < 4; ++j) {
        int row = dt * 16 + g * 4 + j;
        O[dt][j] = O[dt][j] * f0 + OBl[0][row][lo] * f1 +
                   OBl[1][row][lo] * f2 + OBl[2][row][lo] * f3;
      }
    f16x8 fb = *(const f16x8*)&fwlds[lo][g * 8];
#pragma unroll
    for (int dt = 0; dt < 4; ++dt) {
      f16x8 va = *(const f16x8*)(Vw + (long)(dt * 16 + lo) * RS_ + g * 8);
      O[dt] = mf16(va, fb, O[dt]);
    }
#pragma unroll
    for (int dt = 0; dt < 4; ++dt)
#pragma unroll
      for (int j = 0; j < 4; ++j) Olds[lo][dt * 16 + g * 4 + j] = O[dt][j];
  }
  __syncthreads();
  for (int idx = tid; idx < 16 * 64; idx += 256) {
    int row = idx >> 6;
    int col = idx & 63;
    AO[((long)(b * S_ + s0 + row)) * E_ + h * 64 + col] = (_Float16)Olds[row][col];
  }
}

// ---------------------------------------------------------------------------
// Kernel 4: MFMA output projection. C[n,e] = sum_f AO16[n,f]*Wo[e,f] + bo[e].
// ---------------------------------------------------------------------------
__global__ __launch_bounds__(256) void out_proj_mfma(const _Float16* __restrict__ AO16,
                                                     const float* __restrict__ Wo,
                                                     const float* __restrict__ bo,
                                                     float* __restrict__ Out) {
  __shared__ alignas(16) _Float16 As[2][64][72];
  __shared__ alignas(16) _Float16 Bs[2][64][72];

  int tid = threadIdx.x;
  int blk = blockIdx.x;
  int et = blk % 12;
  int nt = blk / 12;
  int n0 = nt * 64, e0 = et * 64;
  int w = tid >> 6, l = tid & 63, lo = l & 15, g = l >> 4;
  int i = tid >> 2, part = tid & 3;

  const _Float16* aop = AO16 + (long)(n0 + i) * E_ + part * 16;
  const float* wop = Wo + (long)(e0 + i) * E_ + part * 16;

  f32x4 acc[4];
#pragma unroll
  for (int ns = 0; ns < 4; ++ns)
#pragma unroll
    for (int q = 0; q < 4; ++q) acc[ns][q] = 0.f;

  auto STAGE = [&](int kb, int bufi) {
    const uint4* ap4 = (const uint4*)(aop + kb);
    uint4 a0 = ap4[0], a1 = ap4[1];
    *(uint4*)&As[bufi][i][part * 16]     = a0;
    *(uint4*)&As[bufi][i][part * 16 + 8] = a1;
    const float4* p = (const float4*)(wop + kb);
    float4 x0 = p[0], x1 = p[1], x2 = p[2], x3 = p[3];
    *(f16x8*)&Bs[bufi][i][part * 16]     = cvt8(x0, x1);
    *(f16x8*)&Bs[bufi][i][part * 16 + 8] = cvt8(x2, x3);
  };

  STAGE(0, 0);
  __syncthreads();
  for (int k = 0; k < 12; ++k) {
    if (k < 11) STAGE((k + 1) * 64, (k + 1) & 1);
    int bi = k & 1;
#pragma unroll
    for (int kc = 0; kc < 2; ++kc) {
      f16x8 af = *(const f16x8*)&As[bi][w * 16 + lo][kc * 32 + g * 8];
#pragma unroll
      for (int ns = 0; ns < 4; ++ns) {
        f16x8 bf = *(const f16x8*)&Bs[bi][ns * 16 + lo][kc * 32 + g * 8];
        acc[ns] = mf16(af, bf, acc[ns]);
      }
    }
    __syncthreads();
  }

  float* Cs = (float*)&As[0][0][0];  // Cs[n][e], stride 69
#pragma unroll
  for (int ns = 0; ns < 4; ++ns)
#pragma unroll
    for (int reg = 0; reg < 4; ++reg)
      Cs[(w * 16 + g * 4 + reg) * 69 + ns * 16 + lo] = acc[ns][reg];
  __syncthreads();

  float tmp[16];
#pragma unroll
  for (int q = 0; q < 16; ++q)
    tmp[q] = Cs[i * 69 + part * 16 + q] + bo[e0 + part * 16 + q];
  float* outp = Out + (long)(n0 + i) * E_ + e0 + part * 16;
#pragma unroll
  for (int q4 = 0; q4 < 4; ++q4)
    ((float4*)outp)[q4] = make_float4(tmp[q4 * 4], tmp[q4 * 4 + 1], tmp[q4 * 4 + 2], tmp[q4 * 4 + 3]);
}

extern "C" void kernel_launch(void* const* d_in, const int* in_sizes, int n_in,
                              void* d_out, int out_size, void* d_ws, size_t ws_size,
                              hipStream_t stream) {
  const float* query = (const float*)d_in[0];
  const float* key   = (const float*)d_in[1];
  const float* value = (const float*)d_in[2];
  const float* rk    = (const float*)d_in[3];
  const float* rw    = (const float*)d_in[4];
  const float* Wq    = (const float*)d_in[5];
  const float* Wk    = (const float*)d_in[6];
  const float* Wv    = (const float*)d_in[7];
  const float* bv    = (const float*)d_in[8];
  const float* Wo    = (const float*)d_in[9];
  const float* bo    = (const float*)d_in[10];
  float* out = (float*)d_out;

  char* wsb = (char*)d_ws;
  _Float16* Qh   = (_Float16*)(wsb);                 // 3,145,728 B
  _Float16* Kh   = (_Float16*)(wsb + 3145728);       // 3,145,728 B
  _Float16* VPT  = (_Float16*)(wsb + 6291456);       // 3,244,032 B
  _Float16* AO16 = (_Float16*)(wsb + 9535488);       // 3,145,728 B
  __bf16* W1b = (__bf16*)(wsb + 12681216);           // 49,152 B
  __bf16* W2b = (__bf16*)(wsb + 12730368);           // 49,152 B
  float* cb   = (float*)(wsb + 12779520);            // 1,536 B

  prep_rules<<<384, 64, 0, stream>>>(rk, rw, W1b, W2b, cb);
  qk_proj_mfma<<<384, 256, 0, stream>>>(query, key, Wq, Wk, Qh, Kh);
  v_proj_mfma<<<2 * 17 * 12, 256, 0, stream>>>(Wv, bv, value, VPT);
  attn_mfma<<<1536, 256, 0, stream>>>(Qh, Kh, VPT, W1b, W2b, cb, AO16);
  out_proj_mfma<<<32 * 12, 256, 0, stream>>>(AO16, Wo, bo, out);
}

// Round 12
// 99.672 us; speedup vs baseline: 7.4689x; 1.0089x over previous
//
#include <hip/hip_runtime.h>

#define S_ 1024
#define E_ 768
#define H_ 12
#define R_ 32
#define D_ 64
#define RS_ 1056  // R_+S_

// exp2-domain constants: L = log2(e), LN2 = 1/L
#define L2E 1.4426950408889634f
#define LN2F 0.6931471805599453f

#if __has_builtin(__builtin_amdgcn_exp2f)
#define EXP2(x) __builtin_amdgcn_exp2f(x)
#else
#define EXP2(x) exp2f(x)
#endif

typedef _Float16 f16x8 __attribute__((ext_vector_type(8)));
typedef __fp16   fp16x2 __attribute__((ext_vector_type(2)));  // cvt_pkrtz return type
typedef __bf16   bf16x8 __attribute__((ext_vector_type(8)));
typedef float    f32x4 __attribute__((ext_vector_type(4)));

__device__ __forceinline__ f32x4 mf16(f16x8 a, f16x8 b, f32x4 c) {
  return __builtin_amdgcn_mfma_f32_16x16x32_f16(a, b, c, 0, 0, 0);
}
__device__ __forceinline__ f32x4 mbf(bf16x8 a, bf16x8 b, f32x4 c) {
  return __builtin_amdgcn_mfma_f32_16x16x32_bf16(a, b, c, 0, 0, 0);
}
__device__ __forceinline__ f16x8 cvt8(float4 a, float4 b) {
  f16x8 r;
  r[0] = (_Float16)a.x; r[1] = (_Float16)a.y; r[2] = (_Float16)a.z; r[3] = (_Float16)a.w;
  r[4] = (_Float16)b.x; r[5] = (_Float16)b.y; r[6] = (_Float16)b.z; r[7] = (_Float16)b.w;
  return r;
}

// ---------------------------------------------------------------------------
// Prep: fold fuzzy quadratic form into GEMM operands, exp2 domain.
// ---------------------------------------------------------------------------
__global__ __launch_bounds__(64) void prep_rules(const float* __restrict__ RK,
                                                 const float* __restrict__ RW,
                                                 __bf16* __restrict__ W1b,
                                                 __bf16* __restrict__ W2b,
                                                 float* __restrict__ cb) {
  int hr = blockIdx.x;  // 0..383 = h*32 + r
  int d = threadIdx.x;
  long idx = (long)hr * 64 + d;
  float w = RW[idx];
  float wi = 1.0f / w;
  float w2 = wi * wi;
  float rk = RK[idx];
  W1b[idx] = (__bf16)(-w2 * (LN2F / 524288.0f));
  W2b[idx] = (__bf16)(rk * w2 * (1.0f / 4096.0f));
  float part = rk * rk * w2;
  part += __shfl_xor(part, 1);
  part += __shfl_xor(part, 2);
  part += __shfl_xor(part, 4);
  part += __shfl_xor(part, 8);
  part += __shfl_xor(part, 16);
  part += __shfl_xor(part, 32);
  if (d == 0) cb[hr] = -part * (L2E / 128.0f);
}

// ---------------------------------------------------------------------------
// Kernel 1: per-head Q/K projections via MFMA, zero LDS. Q scaled 8*log2(e).
// ---------------------------------------------------------------------------
__global__ __launch_bounds__(256) void qk_proj_mfma(const float* __restrict__ query,
                                                    const float* __restrict__ key,
                                                    const float* __restrict__ Wq,
                                                    const float* __restrict__ Wk,
                                                    _Float16* __restrict__ Qh,
                                                    _Float16* __restrict__ Kh) {
  int blk = blockIdx.x;
  int st = blk & 15;
  int h  = (blk >> 4) % H_;
  int b  = blk / (16 * H_);
  int tid = threadIdx.x;
  int w = tid >> 6, l = tid & 63, lo = l & 15, g = l >> 4;

  int s_in = st * 64 + w * 16 + lo;
  const float* qp = query + ((long)(b * S_) + s_in) * E_ + h * 64;
  const float* kp = key   + ((long)(b * S_) + s_in) * E_ + h * 64;
  float4 a0 = *(const float4*)(qp + g * 8);
  float4 a1 = *(const float4*)(qp + g * 8 + 4);
  float4 a2 = *(const float4*)(qp + 32 + g * 8);
  float4 a3 = *(const float4*)(qp + 32 + g * 8 + 4);
  f16x8 xq0 = cvt8(a0, a1), xq1 = cvt8(a2, a3);
  a0 = *(const float4*)(kp + g * 8);
  a1 = *(const float4*)(kp + g * 8 + 4);
  a2 = *(const float4*)(kp + 32 + g * 8);
  a3 = *(const float4*)(kp + 32 + g * 8 + 4);
  f16x8 xk0 = cvt8(a0, a1), xk1 = cvt8(a2, a3);

  f32x4 accq[4], acck[4];
#pragma unroll
  for (int ns = 0; ns < 4; ++ns)
#pragma unroll
    for (int q = 0; q < 4; ++q) { accq[ns][q] = 0.f; acck[ns][q] = 0.f; }

#pragma unroll
  for (int ns = 0; ns < 4; ++ns) {
    const float* wqp = Wq + (long)(ns * 16 + lo) * 64;
    const float* wkp = Wk + (long)(ns * 16 + lo) * 64;
    float4 b0 = *(const float4*)(wqp + g * 8);
    float4 b1 = *(const float4*)(wqp + g * 8 + 4);
    float4 b2 = *(const float4*)(wqp + 32 + g * 8);
    float4 b3 = *(const float4*)(wqp + 32 + g * 8 + 4);
    f16x8 bq0 = cvt8(b0, b1), bq1 = cvt8(b2, b3);
    b0 = *(const float4*)(wkp + g * 8);
    b1 = *(const float4*)(wkp + g * 8 + 4);
    b2 = *(const float4*)(wkp + 32 + g * 8);
    b3 = *(const float4*)(wkp + 32 + g * 8 + 4);
    f16x8 bk0 = cvt8(b0, b1), bk1 = cvt8(b2, b3);
    accq[ns] = mf16(xq0, bq0, accq[ns]);
    accq[ns] = mf16(xq1, bq1, accq[ns]);
    acck[ns] = mf16(xk0, bk0, acck[ns]);
    acck[ns] = mf16(xk1, bk1, acck[ns]);
  }

  long rowbase = (long)(b * H_ + h) * S_ + st * 64 + w * 16;
#pragma unroll
  for (int ns = 0; ns < 4; ++ns) {
#pragma unroll
    for (int reg = 0; reg < 4; ++reg) {
      long off = (rowbase + g * 4 + reg) * 64 + ns * 16 + lo;
      Qh[off] = (_Float16)(accq[ns][reg] * (8.0f * L2E));
      Kh[off] = (_Float16)acck[ns][reg];
    }
  }
}

// ---------------------------------------------------------------------------
// Kernel 2: MFMA value projection, value staged directly (fused transpose).
// ---------------------------------------------------------------------------
__global__ __launch_bounds__(256) void v_proj_mfma(const float* __restrict__ Wv,
                                                   const float* __restrict__ bv,
                                                   const float* __restrict__ value,
                                                   _Float16* __restrict__ VPT) {
  __shared__ alignas(16) _Float16 As[2][64][72];
  __shared__ alignas(16) _Float16 Bs[2][64][72];

  int tid = threadIdx.x;
  int blk = blockIdx.x;
  int et = blk % 12;
  int rt = (blk / 12) % 17;
  int b  = blk / (12 * 17);
  int r0 = rt * 64, e0 = et * 64;
  int w = tid >> 6, l = tid & 63, lo = l & 15, g = l >> 4;
  int i = tid >> 2, part = tid & 3;

  bool rvalid = (r0 + i) < RS_;
  const float* wvp = Wv + (long)(r0 + i) * S_ + part * 16;
  const float* vbase = value + (long)(b * S_) * E_ + e0 + part * 16;

  f32x4 acc[4];
#pragma unroll
  for (int ns = 0; ns < 4; ++ns)
#pragma unroll
    for (int q = 0; q < 4; ++q) acc[ns][q] = 0.f;

  auto STAGE = [&](int kb, int bufi) {
    float4 x0, x1, x2, x3;
    if (rvalid) {
      const float4* p = (const float4*)(wvp + kb);
      x0 = p[0]; x1 = p[1]; x2 = p[2]; x3 = p[3];
    } else {
      x0 = x1 = x2 = x3 = make_float4(0.f, 0.f, 0.f, 0.f);
    }
    *(f16x8*)&As[bufi][i][part * 16]     = cvt8(x0, x1);
    *(f16x8*)&As[bufi][i][part * 16 + 8] = cvt8(x2, x3);
    const float4* vp = (const float4*)(vbase + (long)(kb + i) * E_);
    float4 y0 = vp[0], y1 = vp[1], y2 = vp[2], y3 = vp[3];
    Bs[bufi][part * 16 +  0][i] = (_Float16)y0.x;
    Bs[bufi][part * 16 +  1][i] = (_Float16)y0.y;
    Bs[bufi][part * 16 +  2][i] = (_Float16)y0.z;
    Bs[bufi][part * 16 +  3][i] = (_Float16)y0.w;
    Bs[bufi][part * 16 +  4][i] = (_Float16)y1.x;
    Bs[bufi][part * 16 +  5][i] = (_Float16)y1.y;
    Bs[bufi][part * 16 +  6][i] = (_Float16)y1.z;
    Bs[bufi][part * 16 +  7][i] = (_Float16)y1.w;
    Bs[bufi][part * 16 +  8][i] = (_Float16)y2.x;
    Bs[bufi][part * 16 +  9][i] = (_Float16)y2.y;
    Bs[bufi][part * 16 + 10][i] = (_Float16)y2.z;
    Bs[bufi][part * 16 + 11][i] = (_Float16)y2.w;
    Bs[bufi][part * 16 + 12][i] = (_Float16)y3.x;
    Bs[bufi][part * 16 + 13][i] = (_Float16)y3.y;
    Bs[bufi][part * 16 + 14][i] = (_Float16)y3.z;
    Bs[bufi][part * 16 + 15][i] = (_Float16)y3.w;
  };

  STAGE(0, 0);
  __syncthreads();
  for (int k = 0; k < 16; ++k) {
    if (k < 15) STAGE((k + 1) * 64, (k + 1) & 1);
    int bi = k & 1;
#pragma unroll
    for (int kc = 0; kc < 2; ++kc) {
      f16x8 af = *(const f16x8*)&As[bi][w * 16 + lo][kc * 32 + g * 8];
#pragma unroll
      for (int ns = 0; ns < 4; ++ns) {
        f16x8 bf = *(const f16x8*)&Bs[bi][ns * 16 + lo][kc * 32 + g * 8];
        acc[ns] = mf16(af, bf, acc[ns]);
      }
    }
    __syncthreads();
  }

  float bvr[4];
#pragma unroll
  for (int reg = 0; reg < 4; ++reg) {
    int r = r0 + w * 16 + g * 4 + reg;
    bvr[reg] = (r < RS_) ? bv[r] : 0.f;
  }
  float* Ct = (float*)&As[0][0][0];  // Ct[d][rloc], stride 69
#pragma unroll
  for (int ns = 0; ns < 4; ++ns)
#pragma unroll
    for (int reg = 0; reg < 4; ++reg)
      Ct[(ns * 16 + lo) * 69 + w * 16 + g * 4 + reg] = acc[ns][reg] + bvr[reg];
  __syncthreads();

  if (r0 + part * 16 < RS_) {
    f16x8 o0, o1;
#pragma unroll
    for (int q = 0; q < 8; ++q) o0[q] = (_Float16)Ct[i * 69 + part * 16 + q];
#pragma unroll
    for (int q = 0; q < 8; ++q) o1[q] = (_Float16)Ct[i * 69 + part * 16 + 8 + q];
    _Float16* op = VPT + ((long)((b * H_ + et) * 64 + i)) * RS_ + r0 + part * 16;
    *(f16x8*)op = o0;
    *((f16x8*)op + 1) = o1;
  }
}

// ---------------------------------------------------------------------------
// Kernel 3: MFMA flash attention, 32-row q-tile (2 q-subtiles x 2 key-halves).
// Halves per-(b,h) K/V re-reads vs 16-row tiles. grid = B*H*32 = 768.
// ---------------------------------------------------------------------------
__global__ __launch_bounds__(256) void attn_mfma(
    const _Float16* __restrict__ Qh, const _Float16* __restrict__ Kh,
    const _Float16* __restrict__ VPT, const __bf16* __restrict__ W1b,
    const __bf16* __restrict__ W2b, const float* __restrict__ cb,
    _Float16* __restrict__ AO) {
  __shared__ alignas(16) _Float16 Plds[4][16][40];   // [wave][q=lo][key]
  __shared__ alignas(16) _Float16 fwlds[2][16][40];  // [qsub][q=lo][rule]
  __shared__ float OBl[2][64][17];                   // half==1 O spill per qsub
  __shared__ float mrgM[2][16];
  __shared__ float mrgL[2][16];
  __shared__ float Olds[2][16][68];

  int tid = threadIdx.x;
  int wv = tid >> 6;            // wave id
  int qsub = wv >> 1;           // 0/1: q-subtile
  int half = wv & 1;            // 0/1: key half
  int l = tid & 63;
  int lo = l & 15, g = l >> 4;

  int bh = blockIdx.x >> 5;
  int qt = blockIdx.x & 31;
  int b = bh / H_, h = bh % H_;
  int s0 = qt * 32;

  const _Float16* Qw = Qh + ((long)bh * S_ + s0 + qsub * 16) * 64;
  const _Float16* Kw = Kh + (long)bh * S_ * 64;
  const _Float16* Vw = VPT + (long)bh * 64 * RS_;

  f16x8 qa0 = *(const f16x8*)(Qw + (long)lo * 64 + g * 8);
  f16x8 qa1 = *(const f16x8*)(Qw + (long)lo * 64 + 32 + g * 8);

  // ---- fuzzy branch (half==0 waves, one per qsub), exp2 domain
  if (half == 0) {
    bf16x8 qsq0, qsq1, qbf0, qbf1;
#pragma unroll
    for (int j = 0; j < 8; ++j) {
      float a0 = (float)qa0[j], a1 = (float)qa1[j];
      qbf0[j] = (__bf16)a0;
      qbf1[j] = (__bf16)a1;
      qsq0[j] = (__bf16)(a0 * a0);
      qsq1[j] = (__bf16)(a1 * a1);
    }
    f32x4 z[2];
#pragma unroll
    for (int t = 0; t < 2; ++t) {
#pragma unroll
      for (int j = 0; j < 4; ++j) z[t][j] = cb[h * R_ + t * 16 + g * 4 + j];
      const __bf16* w1p = W1b + ((long)h * R_ + t * 16 + lo) * 64;
      const __bf16* w2p = W2b + ((long)h * R_ + t * 16 + lo) * 64;
      bf16x8 b10 = *(const bf16x8*)(w1p + g * 8);
      bf16x8 b11 = *(const bf16x8*)(w1p + 32 + g * 8);
      bf16x8 b20 = *(const bf16x8*)(w2p + g * 8);
      bf16x8 b21 = *(const bf16x8*)(w2p + 32 + g * 8);
      z[t] = mbf(b10, qsq0, z[t]);
      z[t] = mbf(b11, qsq1, z[t]);
      z[t] = mbf(b20, qbf0, z[t]);
      z[t] = mbf(b21, qbf1, z[t]);
    }
    float zm = z[0][0];
#pragma unroll
    for (int j = 1; j < 4; ++j) zm = fmaxf(zm, z[0][j]);
#pragma unroll
    for (int j = 0; j < 4; ++j) zm = fmaxf(zm, z[1][j]);
    zm = fmaxf(zm, __shfl_xor(zm, 16));
    zm = fmaxf(zm, __shfl_xor(zm, 32));
    float ez[2][4], zsum = 0.f;
#pragma unroll
    for (int t = 0; t < 2; ++t)
#pragma unroll
      for (int j = 0; j < 4; ++j) { ez[t][j] = EXP2(z[t][j] - zm); zsum += ez[t][j]; }
    zsum += __shfl_xor(zsum, 16);
    zsum += __shfl_xor(zsum, 32);
    float zin = 1.0f / zsum;
#pragma unroll
    for (int t = 0; t < 2; ++t)
#pragma unroll
      for (int j = 0; j < 4; ++j)
        fwlds[qsub][lo][t * 16 + g * 4 + j] = (_Float16)(ez[t][j] * zin);
  }

  // ---- flash key loop: 16 chunks of 32 keys (this wave's key half)
  f32x4 O[4];
#pragma unroll
  for (int dt = 0; dt < 4; ++dt)
#pragma unroll
    for (int j = 0; j < 4; ++j) O[dt][j] = 0.f;
  float m = -__builtin_inff();
  float ellp = 0.f;

  int kb0 = half * 512;
  const _Float16* kp0 = Kw + (long)(kb0 + lo) * 64 + g * 8;
  const _Float16* kp1 = Kw + (long)(kb0 + 16 + lo) * 64 + g * 8;
  f16x8 kf00 = *(const f16x8*)(kp0);
  f16x8 kf01 = *(const f16x8*)(kp0 + 32);
  f16x8 kf10 = *(const f16x8*)(kp1);
  f16x8 kf11 = *(const f16x8*)(kp1 + 32);

  for (int c = 0; c < 16; ++c) {
    int kb = kb0 + c * 32;
    f16x8 nf00, nf01, nf10, nf11;
    if (c < 15) {  // prefetch next chunk's K fragments
      const _Float16* np0 = Kw + (long)(kb + 32 + lo) * 64 + g * 8;
      const _Float16* np1 = Kw + (long)(kb + 48 + lo) * 64 + g * 8;
      nf00 = *(const f16x8*)(np0);
      nf01 = *(const f16x8*)(np0 + 32);
      nf10 = *(const f16x8*)(np1);
      nf11 = *(const f16x8*)(np1 + 32);
    }
    f32x4 e0, e1;
#pragma unroll
    for (int j = 0; j < 4; ++j) { e0[j] = 0.f; e1[j] = 0.f; }
    e0 = mf16(kf00, qa0, e0);  // e0[j]: key kb+g*4+j, q=lo (exp2 domain)
    e0 = mf16(kf01, qa1, e0);
    e1 = mf16(kf10, qa0, e1);  // keys kb+16+g*4+j
    e1 = mf16(kf11, qa1, e1);

    // issue V loads early (no dependence on e)
    f16x8 va0 = *(const f16x8*)(Vw + (long)(0 * 16 + lo) * RS_ + R_ + kb + g * 8);
    f16x8 va1 = *(const f16x8*)(Vw + (long)(1 * 16 + lo) * RS_ + R_ + kb + g * 8);
    f16x8 va2 = *(const f16x8*)(Vw + (long)(2 * 16 + lo) * RS_ + R_ + kb + g * 8);
    f16x8 va3 = *(const f16x8*)(Vw + (long)(3 * 16 + lo) * RS_ + R_ + kb + g * 8);

    // speculative exps with stale m (overlaps the pmax reduce)
    float p0[4], p1[4];
#pragma unroll
    for (int j = 0; j < 4; ++j) {
      p0[j] = EXP2(e0[j] - m);
      p1[j] = EXP2(e1[j] - m);
    }
    float pmax = e0[0];
#pragma unroll
    for (int j = 1; j < 4; ++j) pmax = fmaxf(pmax, e0[j]);
#pragma unroll
    for (int j = 0; j < 4; ++j) pmax = fmaxf(pmax, e1[j]);
    pmax = fmaxf(pmax, __shfl_xor(pmax, 16));
    pmax = fmaxf(pmax, __shfl_xor(pmax, 32));
    if (__any(pmax > m + 11.5f)) {  // rescale needed (rare): redo
      float mn = fmaxf(m, pmax);
      float sc = EXP2(m - mn);
      ellp *= sc;
#pragma unroll
      for (int dt = 0; dt < 4; ++dt)
#pragma unroll
        for (int j = 0; j < 4; ++j) O[dt][j] *= sc;
#pragma unroll
      for (int j = 0; j < 4; ++j) {
        p0[j] = EXP2(e0[j] - mn);
        p1[j] = EXP2(e1[j] - mn);
      }
      m = mn;
    }
    float s8 = 0.f;
#pragma unroll
    for (int j = 0; j < 4; ++j) s8 += p0[j] + p1[j];
    ellp += s8;
    // packed P write: 4 x b32 instead of 8 x b16
    fp16x2 w0 = __builtin_amdgcn_cvt_pkrtz(p0[0], p0[1]);
    fp16x2 w1 = __builtin_amdgcn_cvt_pkrtz(p0[2], p0[3]);
    fp16x2 w2 = __builtin_amdgcn_cvt_pkrtz(p1[0], p1[1]);
    fp16x2 w3 = __builtin_amdgcn_cvt_pkrtz(p1[2], p1[3]);
    *(fp16x2*)&Plds[wv][lo][g * 4]          = w0;
    *(fp16x2*)&Plds[wv][lo][g * 4 + 2]      = w1;
    *(fp16x2*)&Plds[wv][lo][16 + g * 4]     = w2;
    *(fp16x2*)&Plds[wv][lo][16 + g * 4 + 2] = w3;
    f16x8 pb = *(const f16x8*)&Plds[wv][lo][g * 8];  // B-frag: row q=lo
    O[0] = mf16(va0, pb, O[0]);
    O[1] = mf16(va1, pb, O[1]);
    O[2] = mf16(va2, pb, O[2]);
    O[3] = mf16(va3, pb, O[3]);
    kf00 = nf00; kf01 = nf01; kf10 = nf10; kf11 = nf11;
  }

  // per-wave ell: cross-g reduce
  float ell = ellp;
  ell += __shfl_xor(ell, 16);
  ell += __shfl_xor(ell, 32);

  // ---- merge the pair's two states (per-lane, q = lo)
  if (half == 1) {
#pragma unroll
    for (int dt = 0; dt < 4; ++dt)
#pragma unroll
      for (int j = 0; j < 4; ++j) OBl[qsub][dt * 16 + g * 4 + j][lo] = O[dt][j];
    if (l < 16) {
      mrgM[qsub][l] = m;
      mrgL[qsub][l] = ell;
    }
  }
  __syncthreads();
  if (half == 0) {
    float mB = mrgM[qsub][lo];
    float lB = mrgL[qsub][lo];
    float m12 = fmaxf(m, mB);
    float sA = EXP2(m - m12);
    float sB = EXP2(mB - m12);
    float iv = 1.0f / (ell * sA + lB * sB);
    float fA = sA * iv, fB = sB * iv;
#pragma unroll
    for (int dt = 0; dt < 4; ++dt)
#pragma unroll
      for (int j = 0; j < 4; ++j)
        O[dt][j] = O[dt][j] * fA + OBl[qsub][dt * 16 + g * 4 + j][lo] * fB;
    // rules contribution (already normalized)
    f16x8 fb = *(const f16x8*)&fwlds[qsub][lo][g * 8];
#pragma unroll
    for (int dt = 0; dt < 4; ++dt) {
      f16x8 va = *(const f16x8*)(Vw + (long)(dt * 16 + lo) * RS_ + g * 8);
      O[dt] = mf16(va, fb, O[dt]);
    }
#pragma unroll
    for (int dt = 0; dt < 4; ++dt)
#pragma unroll
      for (int j = 0; j < 4; ++j) Olds[qsub][lo][dt * 16 + g * 4 + j] = O[dt][j];
  }
  __syncthreads();
  for (int idx = tid; idx < 2 * 16 * 64; idx += 256) {
    int pp = idx >> 10;
    int row = (idx >> 6) & 15;
    int col = idx & 63;
    AO[((long)(b * S_ + s0 + pp * 16 + row)) * E_ + h * 64 + col] =
        (_Float16)Olds[pp][row][col];
  }
}

// ---------------------------------------------------------------------------
// Kernel 4: MFMA output projection. C[n,e] = sum_f AO16[n,f]*Wo[e,f] + bo[e].
// ---------------------------------------------------------------------------
__global__ __launch_bounds__(256) void out_proj_mfma(const _Float16* __restrict__ AO16,
                                                     const float* __restrict__ Wo,
                                                     const float* __restrict__ bo,
                                                     float* __restrict__ Out) {
  __shared__ alignas(16) _Float16 As[2][64][72];
  __shared__ alignas(16) _Float16 Bs[2][64][72];

  int tid = threadIdx.x;
  int blk = blockIdx.x;
  int et = blk % 12;
  int nt = blk / 12;
  int n0 = nt * 64, e0 = et * 64;
  int w = tid >> 6, l = tid & 63, lo = l & 15, g = l >> 4;
  int i = tid >> 2, part = tid & 3;

  const _Float16* aop = AO16 + (long)(n0 + i) * E_ + part * 16;
  const float* wop = Wo + (long)(e0 + i) * E_ + part * 16;

  f32x4 acc[4];
#pragma unroll
  for (int ns = 0; ns < 4; ++ns)
#pragma unroll
    for (int q = 0; q < 4; ++q) acc[ns][q] = 0.f;

  auto STAGE = [&](int kb, int bufi) {
    const uint4* ap4 = (const uint4*)(aop + kb);
    uint4 a0 = ap4[0], a1 = ap4[1];
    *(uint4*)&As[bufi][i][part * 16]     = a0;
    *(uint4*)&As[bufi][i][part * 16 + 8] = a1;
    const float4* p = (const float4*)(wop + kb);
    float4 x0 = p[0], x1 = p[1], x2 = p[2], x3 = p[3];
    *(f16x8*)&Bs[bufi][i][part * 16]     = cvt8(x0, x1);
    *(f16x8*)&Bs[bufi][i][part * 16 + 8] = cvt8(x2, x3);
  };

  STAGE(0, 0);
  __syncthreads();
  for (int k = 0; k < 12; ++k) {
    if (k < 11) STAGE((k + 1) * 64, (k + 1) & 1);
    int bi = k & 1;
#pragma unroll
    for (int kc = 0; kc < 2; ++kc) {
      f16x8 af = *(const f16x8*)&As[bi][w * 16 + lo][kc * 32 + g * 8];
#pragma unroll
      for (int ns = 0; ns < 4; ++ns) {
        f16x8 bf = *(const f16x8*)&Bs[bi][ns * 16 + lo][kc * 32 + g * 8];
        acc[ns] = mf16(af, bf, acc[ns]);
      }
    }
    __syncthreads();
  }

  float* Cs = (float*)&As[0][0][0];  // Cs[n][e], stride 69
#pragma unroll
  for (int ns = 0; ns < 4; ++ns)
#pragma unroll
    for (int reg = 0; reg < 4; ++reg)
      Cs[(w * 16 + g * 4 + reg) * 69 + ns * 16 + lo] = acc[ns][reg];
  __syncthreads();

  float tmp[16];
#pragma unroll
  for (int q = 0; q < 16; ++q)
    tmp[q] = Cs[i * 69 + part * 16 + q] + bo[e0 + part * 16 + q];
  float* outp = Out + (long)(n0 + i) * E_ + e0 + part * 16;
#pragma unroll
  for (int q4 = 0; q4 < 4; ++q4)
    ((float4*)outp)[q4] = make_float4(tmp[q4 * 4], tmp[q4 * 4 + 1], tmp[q4 * 4 + 2], tmp[q4 * 4 + 3]);
}

extern "C" void kernel_launch(void* const* d_in, const int* in_sizes, int n_in,
                              void* d_out, int out_size, void* d_ws, size_t ws_size,
                              hipStream_t stream) {
  const float* query = (const float*)d_in[0];
  const float* key   = (const float*)d_in[1];
  const float* value = (const float*)d_in[2];
  const float* rk    = (const float*)d_in[3];
  const float* rw    = (const float*)d_in[4];
  const float* Wq    = (const float*)d_in[5];
  const float* Wk    = (const float*)d_in[6];
  const float* Wv    = (const float*)d_in[7];
  const float* bv    = (const float*)d_in[8];
  const float* Wo    = (const float*)d_in[9];
  const float* bo    = (const float*)d_in[10];
  float* out = (float*)d_out;

  char* wsb = (char*)d_ws;
  _Float16* Qh   = (_Float16*)(wsb);                 // 3,145,728 B
  _Float16* Kh   = (_Float16*)(wsb + 3145728);       // 3,145,728 B
  _Float16* VPT  = (_Float16*)(wsb + 6291456);       // 3,244,032 B
  _Float16* AO16 = (_Float16*)(wsb + 9535488);       // 3,145,728 B
  __bf16* W1b = (__bf16*)(wsb + 12681216);           // 49,152 B
  __bf16* W2b = (__bf16*)(wsb + 12730368);           // 49,152 B
  float* cb   = (float*)(wsb + 12779520);            // 1,536 B

  prep_rules<<<384, 64, 0, stream>>>(rk, rw, W1b, W2b, cb);
  qk_proj_mfma<<<384, 256, 0, stream>>>(query, key, Wq, Wk, Qh, Kh);
  v_proj_mfma<<<2 * 17 * 12, 256, 0, stream>>>(Wv, bv, value, VPT);
  attn_mfma<<<768, 256, 0, stream>>>(Qh, Kh, VPT, W1b, W2b, cb, AO16);
  out_proj_mfma<<<32 * 12, 256, 0, stream>>>(AO16, Wo, bo, out);
}